// Round 1
// baseline (591.112 us; speedup 1.0000x reference)
//
#include <hip/hip_runtime.h>
#include <hip/hip_bf16.h>

#define NSEQ 8
#define LSEQ 9216
#define DMODEL 64
#define DIN 128
#define DST 16
#define NCH 144
#define CLEN 64

__device__ __forceinline__ float bf2fl(unsigned short b) {
  return __uint_as_float(((unsigned)b) << 16);
}
__device__ __forceinline__ unsigned short fl2bf(float f) {
  unsigned u = __float_as_uint(f);
  u += 0x7fffu + ((u >> 16) & 1u);
  return (unsigned short)(u >> 16);
}
__device__ __forceinline__ unsigned pk2(float lo, float hi) {
  return ((unsigned)fl2bf(hi) << 16) | (unsigned)fl2bf(lo);
}
__device__ __forceinline__ void unp8(const uint4 r, float* f) {
  f[0]=__uint_as_float(r.x<<16); f[1]=__uint_as_float(r.x&0xffff0000u);
  f[2]=__uint_as_float(r.y<<16); f[3]=__uint_as_float(r.y&0xffff0000u);
  f[4]=__uint_as_float(r.z<<16); f[5]=__uint_as_float(r.z&0xffff0000u);
  f[6]=__uint_as_float(r.w<<16); f[7]=__uint_as_float(r.w&0xffff0000u);
}
__device__ __forceinline__ float sigm(float x) {
  return __fdividef(1.f, 1.f + __expf(-x));
}

// K1: LayerNorm + in_proj. thread=(n, l, rowgroup of 64). writes xs (rows 0..127), z (128..255) as bf16.
__global__ __launch_bounds__(256) void k_ln_inproj(
    const float* __restrict__ x, const float* __restrict__ nw,
    const float* __restrict__ nb, const float* __restrict__ W,
    unsigned* __restrict__ xs, unsigned* __restrict__ zz)
{
  const int l  = blockIdx.x * 256 + threadIdx.x;
  const int rg = blockIdx.y;
  const int n  = blockIdx.z;

  const float* xp = x + ((size_t)n * DMODEL) * LSEQ + l;
  float v[DMODEL];
  float s0 = 0.f;
#pragma unroll
  for (int j = 0; j < DMODEL; ++j) { v[j] = xp[(size_t)j * LSEQ]; s0 += v[j]; }
  const float mu = s0 * (1.f / DMODEL);
  float s1 = 0.f;
#pragma unroll
  for (int j = 0; j < DMODEL; ++j) { float d = v[j] - mu; s1 += d * d; }
  const float rs = rsqrtf(s1 * (1.f / DMODEL) + 1e-6f);
#pragma unroll
  for (int j = 0; j < DMODEL; ++j) v[j] = (v[j] - mu) * rs * nw[j] + nb[j];

  const int r0 = rg * 64;
  unsigned* op = ((rg < 2) ? xs : zz) + ((size_t)(n * LSEQ + l)) * (DIN / 2) + (rg & 1) * 32;
  for (int rr = 0; rr < 64; rr += 4) {
    const float* w0 = W + (size_t)(r0 + rr) * DMODEL;
    float a0 = 0.f, a1 = 0.f, a2 = 0.f, a3 = 0.f;
#pragma unroll
    for (int j = 0; j < DMODEL; ++j) {
      const float vj = v[j];
      a0 = fmaf(w0[j], vj, a0);
      a1 = fmaf(w0[DMODEL + j], vj, a1);
      a2 = fmaf(w0[2 * DMODEL + j], vj, a2);
      a3 = fmaf(w0[3 * DMODEL + j], vj, a3);
    }
    uint2 pk;
    pk.x = pk2(a0, a1);
    pk.y = pk2(a2, a3);
    *reinterpret_cast<uint2*>(op + (rr >> 1)) = pk;
  }
}

// K2: depthwise causal conv (K=4) + SiLU. thread=(n, l, 8-channel group).
__global__ __launch_bounds__(256) void k_conv(
    const uint4* __restrict__ xs, const float* __restrict__ cw,
    const float* __restrict__ cb, uint4* __restrict__ xc)
{
  const int dg = threadIdx.x & 15;   // channel group (8 ch)
  const int dl = threadIdx.x >> 4;   // token within block
  const int l  = blockIdx.x * 16 + dl;
  const int n  = blockIdx.z;
  const int di0 = dg * 8;

  float acc[8];
#pragma unroll
  for (int e = 0; e < 8; ++e) acc[e] = cb[di0 + e];

  const long rowbase = (long)(n * LSEQ + l) * 16 + dg;  // uint4 index
#pragma unroll
  for (int k = 0; k < 4; ++k) {
    const int ls = l - 3 + k;
    if (ls >= 0) {
      const uint4 r = xs[rowbase + (long)(k - 3) * 16];
      float f[8];
      unp8(r, f);
#pragma unroll
      for (int e = 0; e < 8; ++e) acc[e] = fmaf(f[e], cw[(di0 + e) * 4 + k], acc[e]);
    }
  }
  unsigned o[4];
#pragma unroll
  for (int e = 0; e < 8; e += 2) {
    const float y0 = acc[e] * sigm(acc[e]);
    const float y1 = acc[e + 1] * sigm(acc[e + 1]);
    o[e >> 1] = pk2(y0, y1);
  }
  uint4 pkv; pkv.x = o[0]; pkv.y = o[1]; pkv.z = o[2]; pkv.w = o[3];
  xc[rowbase] = pkv;
}

// K3: x_proj (dt_raw/B/C) + dt_proj + softplus. thread=(n,l).
__global__ __launch_bounds__(256) void k_xproj(
    const uint4* __restrict__ xc, const float* __restrict__ XW,
    const float* __restrict__ DW, const float* __restrict__ dtb,
    unsigned* __restrict__ dt, float* __restrict__ Bm, float* __restrict__ Cm)
{
  const int l = blockIdx.x * 256 + threadIdx.x;
  const int n = blockIdx.z;
  const size_t tok = (size_t)(n * LSEQ + l);

  float xf[DIN];
  {
    const uint4* xp = xc + tok * 16;
#pragma unroll
    for (int q = 0; q < 16; ++q) { uint4 r = xp[q]; unp8(r, xf + q * 8); }
  }

  float dtr[4];
#pragma unroll
  for (int r = 0; r < 4; ++r) {
    const float* w = XW + r * DIN;
    float a0 = 0.f, a1 = 0.f, a2 = 0.f, a3 = 0.f;
#pragma unroll
    for (int j = 0; j < DIN; j += 4) {
      a0 = fmaf(w[j],     xf[j],     a0);
      a1 = fmaf(w[j + 1], xf[j + 1], a1);
      a2 = fmaf(w[j + 2], xf[j + 2], a2);
      a3 = fmaf(w[j + 3], xf[j + 3], a3);
    }
    dtr[r] = (a0 + a1) + (a2 + a3);
  }

  for (int r = 4; r < 36; ++r) {
    const float* w = XW + r * DIN;
    float a0 = 0.f, a1 = 0.f, a2 = 0.f, a3 = 0.f;
#pragma unroll
    for (int j = 0; j < DIN; j += 4) {
      a0 = fmaf(w[j],     xf[j],     a0);
      a1 = fmaf(w[j + 1], xf[j + 1], a1);
      a2 = fmaf(w[j + 2], xf[j + 2], a2);
      a3 = fmaf(w[j + 3], xf[j + 3], a3);
    }
    const float acc = (a0 + a1) + (a2 + a3);
    if (r < 20) Bm[tok * DST + (r - 4)]  = acc;
    else        Cm[tok * DST + (r - 20)] = acc;
  }

  for (int d2 = 0; d2 < DIN; d2 += 2) {
    float t0 = dtb[d2];
    float t1 = dtb[d2 + 1];
#pragma unroll
    for (int r = 0; r < 4; ++r) {
      t0 = fmaf(DW[d2 * 4 + r],       dtr[r], t0);
      t1 = fmaf(DW[(d2 + 1) * 4 + r], dtr[r], t1);
    }
    const float sp0 = fmaxf(t0, 0.f) + log1pf(__expf(-fabsf(t0)));
    const float sp1 = fmaxf(t1, 0.f) + log1pf(__expf(-fabsf(t1)));
    dt[tok * (DIN / 2) + (d2 >> 1)] = pk2(sp0, sp1);
  }
}

// K4: scan pass A — per-chunk (prod a, local scan end). thread=(n, chunk, d).
__global__ __launch_bounds__(128) void k_scanA(
    const unsigned short* __restrict__ dtp, const unsigned short* __restrict__ xcp,
    const float* __restrict__ Bm, const float* __restrict__ A_log,
    float* __restrict__ P, float* __restrict__ S)
{
  const int d = threadIdx.x;
  const int c = blockIdx.x;
  const int n = blockIdx.y;

  float Ar[DST];
#pragma unroll
  for (int s = 0; s < DST; ++s) Ar[s] = -__expf(A_log[d * DST + s]);

  float p[DST], h[DST];
#pragma unroll
  for (int s = 0; s < DST; ++s) { p[s] = 1.f; h[s] = 0.f; }

  const size_t tok0 = (size_t)n * LSEQ + (size_t)c * CLEN;
#pragma unroll 2
  for (int i = 0; i < CLEN; ++i) {
    const size_t tok = tok0 + i;
    const float dtv = bf2fl(dtp[tok * DIN + d]);
    const float xcv = bf2fl(xcp[tok * DIN + d]);
    const float bx = dtv * xcv;
    const float4* bmp = reinterpret_cast<const float4*>(Bm + tok * DST);
    const float4 q0 = bmp[0], q1 = bmp[1], q2 = bmp[2], q3 = bmp[3];
    const float bm[DST] = {q0.x,q0.y,q0.z,q0.w, q1.x,q1.y,q1.z,q1.w,
                           q2.x,q2.y,q2.z,q2.w, q3.x,q3.y,q3.z,q3.w};
#pragma unroll
    for (int s = 0; s < DST; ++s) {
      const float a = __expf(dtv * Ar[s]);
      p[s] *= a;
      h[s] = fmaf(a, h[s], bx * bm[s]);
    }
  }
  const size_t ob = (((size_t)n * NCH + c) * DIN + d) * DST;
#pragma unroll
  for (int s = 0; s < DST; ++s) { P[ob + s] = p[s]; S[ob + s] = h[s]; }
}

// K5: sequential carry combine over chunks. thread = (n,d,s) chain.
__global__ __launch_bounds__(256) void k_comb(
    const float* __restrict__ P, const float* __restrict__ S, float* __restrict__ carry)
{
  const int t = blockIdx.x * 256 + threadIdx.x;  // 16384
  const int s = t & 15;
  const int d = (t >> 4) & 127;
  const int n = t >> 11;
  float h = 0.f;
  for (int c = 0; c < NCH; ++c) {
    const size_t idx = (((size_t)n * NCH + c) * DIN + d) * DST + s;
    carry[idx] = h;
    h = fmaf(P[idx], h, S[idx]);
  }
}

// K6: scan pass C — replay with carry-in, fuse y = C·h + D·xc, gate with silu(z). writes yz (bf16).
__global__ __launch_bounds__(128) void k_scanC(
    const unsigned short* __restrict__ dtp, const unsigned short* __restrict__ xcp,
    const unsigned short* __restrict__ zp,
    const float* __restrict__ Bm, const float* __restrict__ Cm,
    const float* __restrict__ A_log, const float* __restrict__ Dp,
    const float* __restrict__ carry, unsigned short* __restrict__ yz)
{
  const int d = threadIdx.x;
  const int c = blockIdx.x;
  const int n = blockIdx.y;

  float Ar[DST];
#pragma unroll
  for (int s = 0; s < DST; ++s) Ar[s] = -__expf(A_log[d * DST + s]);

  float h[DST];
  const size_t cb = (((size_t)n * NCH + c) * DIN + d) * DST;
#pragma unroll
  for (int s = 0; s < DST; ++s) h[s] = carry[cb + s];
  const float Dv = Dp[d];

  const size_t tok0 = (size_t)n * LSEQ + (size_t)c * CLEN;
#pragma unroll 2
  for (int i = 0; i < CLEN; ++i) {
    const size_t tok = tok0 + i;
    const float dtv = bf2fl(dtp[tok * DIN + d]);
    const float xcv = bf2fl(xcp[tok * DIN + d]);
    const float zv  = bf2fl(zp[tok * DIN + d]);
    const float bx = dtv * xcv;
    const float4* bmp = reinterpret_cast<const float4*>(Bm + tok * DST);
    const float4 b0 = bmp[0], b1 = bmp[1], b2 = bmp[2], b3 = bmp[3];
    const float bm[DST] = {b0.x,b0.y,b0.z,b0.w, b1.x,b1.y,b1.z,b1.w,
                           b2.x,b2.y,b2.z,b2.w, b3.x,b3.y,b3.z,b3.w};
    const float4* cmp = reinterpret_cast<const float4*>(Cm + tok * DST);
    const float4 c0 = cmp[0], c1 = cmp[1], c2 = cmp[2], c3 = cmp[3];
    const float cm[DST] = {c0.x,c0.y,c0.z,c0.w, c1.x,c1.y,c1.z,c1.w,
                           c2.x,c2.y,c2.z,c2.w, c3.x,c3.y,c3.z,c3.w};
    float y = Dv * xcv;
#pragma unroll
    for (int s = 0; s < DST; ++s) {
      const float a = __expf(dtv * Ar[s]);
      h[s] = fmaf(a, h[s], bx * bm[s]);
      y = fmaf(h[s], cm[s], y);
    }
    const float o = y * (zv * sigm(zv));
    yz[tok * DIN + d] = fl2bf(o);
  }
}

// K7: out_proj (128->64) + residual. thread=(n, l, half of 32 output channels).
__global__ __launch_bounds__(256) void k_outproj(
    const uint4* __restrict__ yz, const float* __restrict__ OW,
    const float* __restrict__ xin, float* __restrict__ out)
{
  const int l  = blockIdx.x * 256 + threadIdx.x;
  const int hf = blockIdx.y;
  const int n  = blockIdx.z;
  const size_t tok = (size_t)(n * LSEQ + l);

  float acc[32];
#pragma unroll
  for (int m = 0; m < 32; ++m) acc[m] = 0.f;

  const uint4* yp = yz + tok * 16;
  for (int q = 0; q < 16; ++q) {
    const uint4 r = yp[q];
    float f[8];
    unp8(r, f);
    const float* wbase = OW + (size_t)(hf * 32) * DIN + q * 8;
#pragma unroll
    for (int m = 0; m < 32; ++m) {
      const float* w = wbase + m * DIN;
#pragma unroll
      for (int e = 0; e < 8; ++e) acc[m] = fmaf(w[e], f[e], acc[m]);
    }
  }
#pragma unroll
  for (int m = 0; m < 32; ++m) {
    const size_t o = ((size_t)(n * DMODEL + hf * 32 + m)) * LSEQ + l;
    out[o] = xin[o] + acc[m];
  }
}

extern "C" void kernel_launch(void* const* d_in, const int* in_sizes, int n_in,
                              void* d_out, int out_size, void* d_ws, size_t ws_size,
                              hipStream_t stream)
{
  const float* x    = (const float*)d_in[0];
  const float* nw   = (const float*)d_in[1];
  const float* nb   = (const float*)d_in[2];
  const float* ipw  = (const float*)d_in[3];
  const float* cw   = (const float*)d_in[4];
  const float* cb   = (const float*)d_in[5];
  const float* xpw  = (const float*)d_in[6];
  const float* dpw  = (const float*)d_in[7];
  const float* dpb  = (const float*)d_in[8];
  const float* alog = (const float*)d_in[9];
  const float* dpar = (const float*)d_in[10];
  const float* opw  = (const float*)d_in[11];
  float* out = (float*)d_out;

  char* w = (char*)d_ws;
  const size_t tokch = (size_t)NSEQ * LSEQ * DIN;        // 9,437,184 elements
  unsigned short* xs = (unsigned short*)w; w += tokch * 2;
  unsigned short* zz = (unsigned short*)w; w += tokch * 2;
  unsigned short* xc = (unsigned short*)w; w += tokch * 2;
  unsigned short* dt = (unsigned short*)w; w += tokch * 2;
  float* Bm = (float*)w;    w += (size_t)NSEQ * LSEQ * DST * 4;
  float* Cm = (float*)w;    w += (size_t)NSEQ * LSEQ * DST * 4;
  float* P  = (float*)w;    w += (size_t)NSEQ * NCH * DIN * DST * 4;
  float* S  = (float*)w;    w += (size_t)NSEQ * NCH * DIN * DST * 4;
  float* carry = (float*)w; w += (size_t)NSEQ * NCH * DIN * DST * 4;
  unsigned short* yz = (unsigned short*)w; w += tokch * 2;

  k_ln_inproj<<<dim3(LSEQ / 256, 4, NSEQ), 256, 0, stream>>>(
      x, nw, nb, ipw, (unsigned*)xs, (unsigned*)zz);
  k_conv<<<dim3(LSEQ / 16, 1, NSEQ), 256, 0, stream>>>(
      (const uint4*)xs, cw, cb, (uint4*)xc);
  k_xproj<<<dim3(LSEQ / 256, 1, NSEQ), 256, 0, stream>>>(
      (const uint4*)xc, xpw, dpw, dpb, (unsigned*)dt, Bm, Cm);
  k_scanA<<<dim3(NCH, NSEQ), 128, 0, stream>>>(dt, xc, Bm, alog, P, S);
  k_comb<<<dim3((NSEQ * DIN * DST) / 256), 256, 0, stream>>>(P, S, carry);
  k_scanC<<<dim3(NCH, NSEQ), 128, 0, stream>>>(dt, xc, zz, Bm, Cm, alog, dpar, carry, yz);
  k_outproj<<<dim3(LSEQ / 256, 2, NSEQ), 256, 0, stream>>>(
      (const uint4*)yz, opw, x, out);
}

// Round 2
// 480.402 us; speedup vs baseline: 1.2305x; 1.2305x over previous
//
#include <hip/hip_runtime.h>
#include <hip/hip_bf16.h>

#define NSEQ 8
#define LSEQ 9216
#define DMODEL 64
#define DIN 128
#define DST 16
#define NCH 144
#define CLEN 64

__device__ __forceinline__ float bf2fl(unsigned short b) {
  return __uint_as_float(((unsigned)b) << 16);
}
__device__ __forceinline__ unsigned short fl2bf(float f) {
  unsigned u = __float_as_uint(f);
  u += 0x7fffu + ((u >> 16) & 1u);
  return (unsigned short)(u >> 16);
}
__device__ __forceinline__ unsigned pk2(float lo, float hi) {
  return ((unsigned)fl2bf(hi) << 16) | (unsigned)fl2bf(lo);
}
__device__ __forceinline__ void unp8(const uint4 r, float* f) {
  f[0]=__uint_as_float(r.x<<16); f[1]=__uint_as_float(r.x&0xffff0000u);
  f[2]=__uint_as_float(r.y<<16); f[3]=__uint_as_float(r.y&0xffff0000u);
  f[4]=__uint_as_float(r.z<<16); f[5]=__uint_as_float(r.z&0xffff0000u);
  f[6]=__uint_as_float(r.w<<16); f[7]=__uint_as_float(r.w&0xffff0000u);
}
__device__ __forceinline__ float sigm(float x) {
  return __fdividef(1.f, 1.f + __expf(-x));
}

// K1: LayerNorm + in_proj. thread=(n, l, rowgroup of 64). writes xs (rows 0..127), z (128..255) as bf16.
__global__ __launch_bounds__(256) void k_ln_inproj(
    const float* __restrict__ x, const float* __restrict__ nw,
    const float* __restrict__ nb, const float* __restrict__ W,
    unsigned* __restrict__ xs, unsigned* __restrict__ zz)
{
  const int l  = blockIdx.x * 256 + threadIdx.x;
  const int rg = blockIdx.y;
  const int n  = blockIdx.z;

  const float* xp = x + ((size_t)n * DMODEL) * LSEQ + l;
  float v[DMODEL];
  float s0 = 0.f;
#pragma unroll
  for (int j = 0; j < DMODEL; ++j) { v[j] = xp[(size_t)j * LSEQ]; s0 += v[j]; }
  const float mu = s0 * (1.f / DMODEL);
  float s1 = 0.f;
#pragma unroll
  for (int j = 0; j < DMODEL; ++j) { float d = v[j] - mu; s1 += d * d; }
  const float rs = rsqrtf(s1 * (1.f / DMODEL) + 1e-6f);
#pragma unroll
  for (int j = 0; j < DMODEL; ++j) v[j] = (v[j] - mu) * rs * nw[j] + nb[j];

  const int r0 = rg * 64;
  unsigned* op = ((rg < 2) ? xs : zz) + ((size_t)(n * LSEQ + l)) * (DIN / 2) + (rg & 1) * 32;
  for (int rr = 0; rr < 64; rr += 4) {
    const float* w0 = W + (size_t)(r0 + rr) * DMODEL;
    float a0 = 0.f, a1 = 0.f, a2 = 0.f, a3 = 0.f;
#pragma unroll
    for (int j = 0; j < DMODEL; ++j) {
      const float vj = v[j];
      a0 = fmaf(w0[j], vj, a0);
      a1 = fmaf(w0[DMODEL + j], vj, a1);
      a2 = fmaf(w0[2 * DMODEL + j], vj, a2);
      a3 = fmaf(w0[3 * DMODEL + j], vj, a3);
    }
    uint2 pk;
    pk.x = pk2(a0, a1);
    pk.y = pk2(a2, a3);
    *reinterpret_cast<uint2*>(op + (rr >> 1)) = pk;
  }
}

// K2: depthwise causal conv (K=4) + SiLU. thread=(n, l, 8-channel group).
__global__ __launch_bounds__(256) void k_conv(
    const uint4* __restrict__ xs, const float* __restrict__ cw,
    const float* __restrict__ cb, uint4* __restrict__ xc)
{
  const int dg = threadIdx.x & 15;   // channel group (8 ch)
  const int dl = threadIdx.x >> 4;   // token within block
  const int l  = blockIdx.x * 16 + dl;
  const int n  = blockIdx.z;
  const int di0 = dg * 8;

  float acc[8];
#pragma unroll
  for (int e = 0; e < 8; ++e) acc[e] = cb[di0 + e];

  const long rowbase = (long)(n * LSEQ + l) * 16 + dg;  // uint4 index
#pragma unroll
  for (int k = 0; k < 4; ++k) {
    const int ls = l - 3 + k;
    if (ls >= 0) {
      const uint4 r = xs[rowbase + (long)(k - 3) * 16];
      float f[8];
      unp8(r, f);
#pragma unroll
      for (int e = 0; e < 8; ++e) acc[e] = fmaf(f[e], cw[(di0 + e) * 4 + k], acc[e]);
    }
  }
  unsigned o[4];
#pragma unroll
  for (int e = 0; e < 8; e += 2) {
    const float y0 = acc[e] * sigm(acc[e]);
    const float y1 = acc[e + 1] * sigm(acc[e + 1]);
    o[e >> 1] = pk2(y0, y1);
  }
  uint4 pkv; pkv.x = o[0]; pkv.y = o[1]; pkv.z = o[2]; pkv.w = o[3];
  xc[rowbase] = pkv;
}

// K3: x_proj (dt_raw/B/C) + dt_proj + softplus.
// block = 256 threads = 4 waves; block handles 64 tokens; wave g handles a
// row-group (8 of the 32 B/C rows) + 32 dt channels; lane = token.
// Outputs staged in padded LDS, copied out flat-coalesced.
__global__ __launch_bounds__(256) void k_xproj(
    const uint4* __restrict__ xc, const float* __restrict__ XW,
    const float* __restrict__ DW, const float* __restrict__ dtb,
    unsigned* __restrict__ dt, float* __restrict__ Bm, float* __restrict__ Cm)
{
  __shared__ float bs[64][17];
  __shared__ float cs[64][17];
  __shared__ unsigned dts[64][65];

  const int tid  = threadIdx.x;
  const int tok0 = blockIdx.x * 64;
  const int lane = tid & 63;
  const int g    = __builtin_amdgcn_readfirstlane(tid) >> 6;  // wave id 0..3
  const int tok  = lane;

  float dtr[4] = {0.f, 0.f, 0.f, 0.f};
  float acc[8] = {0.f, 0.f, 0.f, 0.f, 0.f, 0.f, 0.f, 0.f};
  const int r0 = 4 + g * 8;
  const float* __restrict__ wB = XW + (size_t)r0 * DIN;

  const uint4* __restrict__ xp = xc + ((size_t)(tok0 + tok)) * 16;
#pragma unroll
  for (int q = 0; q < 16; ++q) {
    const uint4 r = xp[q];
    float f[8];
    unp8(r, f);
#pragma unroll
    for (int e = 0; e < 8; ++e) {
      const int j = q * 8 + e;
      const float v = f[e];
#pragma unroll
      for (int rr = 0; rr < 4; ++rr) dtr[rr] = fmaf(XW[rr * DIN + j], v, dtr[rr]);
#pragma unroll
      for (int rr = 0; rr < 8; ++rr) acc[rr] = fmaf(wB[rr * DIN + j], v, acc[rr]);
    }
  }

  // stage B / C rows
  if (g < 2) {
#pragma unroll
    for (int e = 0; e < 8; ++e) bs[tok][g * 8 + e] = acc[e];
  } else {
#pragma unroll
    for (int e = 0; e < 8; ++e) cs[tok][(g - 2) * 8 + e] = acc[e];
  }

  // dt_proj + softplus for this wave's 32 channels
  const int d0 = g * 32;
#pragma unroll
  for (int e = 0; e < 16; ++e) {
    const int d2 = d0 + 2 * e;
    float t0 = dtb[d2];
    float t1 = dtb[d2 + 1];
#pragma unroll
    for (int r = 0; r < 4; ++r) {
      t0 = fmaf(DW[d2 * 4 + r],       dtr[r], t0);
      t1 = fmaf(DW[(d2 + 1) * 4 + r], dtr[r], t1);
    }
    const float sp0 = fmaxf(t0, 0.f) + log1pf(__expf(-fabsf(t0)));
    const float sp1 = fmaxf(t1, 0.f) + log1pf(__expf(-fabsf(t1)));
    dts[tok][g * 16 + e] = pk2(sp0, sp1);
  }
  __syncthreads();

  // coalesced copy-out (LDS flat, skipping pads)
  {
    unsigned* __restrict__ dtg = dt + (size_t)tok0 * 64;
    const unsigned* dfl = &dts[0][0];
#pragma unroll
    for (int i = 0; i < 16; ++i) {
      const int f = i * 256 + tid;           // 0..4095
      dtg[f] = dfl[f + (f >> 6)];
    }
    float* __restrict__ bg = Bm + (size_t)tok0 * 16;
    float* __restrict__ cg = Cm + (size_t)tok0 * 16;
    const float* bfl = &bs[0][0];
    const float* cfl = &cs[0][0];
#pragma unroll
    for (int i = 0; i < 4; ++i) {
      const int f = i * 256 + tid;           // 0..1023
      bg[f] = bfl[f + (f >> 4)];
      cg[f] = cfl[f + (f >> 4)];
    }
  }
}

// K4: scan pass A — per-chunk (prod a, local scan end). thread=(n, chunk, d).
__global__ __launch_bounds__(128) void k_scanA(
    const unsigned short* __restrict__ dtp, const unsigned short* __restrict__ xcp,
    const float* __restrict__ Bm, const float* __restrict__ A_log,
    float* __restrict__ P, float* __restrict__ S)
{
  const int d = threadIdx.x;
  const int c = blockIdx.x;
  const int n = blockIdx.y;

  float Ar[DST];
#pragma unroll
  for (int s = 0; s < DST; ++s) Ar[s] = -__expf(A_log[d * DST + s]);

  float p[DST], h[DST];
#pragma unroll
  for (int s = 0; s < DST; ++s) { p[s] = 1.f; h[s] = 0.f; }

  const size_t tok0 = (size_t)n * LSEQ + (size_t)c * CLEN;
#pragma unroll 2
  for (int i = 0; i < CLEN; ++i) {
    const size_t tok = tok0 + i;
    const float dtv = bf2fl(dtp[tok * DIN + d]);
    const float xcv = bf2fl(xcp[tok * DIN + d]);
    const float bx = dtv * xcv;
    const float4* bmp = reinterpret_cast<const float4*>(Bm + tok * DST);
    const float4 q0 = bmp[0], q1 = bmp[1], q2 = bmp[2], q3 = bmp[3];
    const float bm[DST] = {q0.x,q0.y,q0.z,q0.w, q1.x,q1.y,q1.z,q1.w,
                           q2.x,q2.y,q2.z,q2.w, q3.x,q3.y,q3.z,q3.w};
#pragma unroll
    for (int s = 0; s < DST; ++s) {
      const float a = __expf(dtv * Ar[s]);
      p[s] *= a;
      h[s] = fmaf(a, h[s], bx * bm[s]);
    }
  }
  const size_t ob = (((size_t)n * NCH + c) * DIN + d) * DST;
#pragma unroll
  for (int s = 0; s < DST; ++s) { P[ob + s] = p[s]; S[ob + s] = h[s]; }
}

// K5: sequential carry combine over chunks. thread = (n,d,s) chain.
__global__ __launch_bounds__(256) void k_comb(
    const float* __restrict__ P, const float* __restrict__ S, float* __restrict__ carry)
{
  const int t = blockIdx.x * 256 + threadIdx.x;  // 16384
  const int s = t & 15;
  const int d = (t >> 4) & 127;
  const int n = t >> 11;
  float h = 0.f;
  for (int c = 0; c < NCH; ++c) {
    const size_t idx = (((size_t)n * NCH + c) * DIN + d) * DST + s;
    carry[idx] = h;
    h = fmaf(P[idx], h, S[idx]);
  }
}

// K6: scan pass C — replay with carry-in, fuse y = C·h + D·xc, gate with silu(z). writes yz (bf16).
__global__ __launch_bounds__(128) void k_scanC(
    const unsigned short* __restrict__ dtp, const unsigned short* __restrict__ xcp,
    const unsigned short* __restrict__ zp,
    const float* __restrict__ Bm, const float* __restrict__ Cm,
    const float* __restrict__ A_log, const float* __restrict__ Dp,
    const float* __restrict__ carry, unsigned short* __restrict__ yz)
{
  const int d = threadIdx.x;
  const int c = blockIdx.x;
  const int n = blockIdx.y;

  float Ar[DST];
#pragma unroll
  for (int s = 0; s < DST; ++s) Ar[s] = -__expf(A_log[d * DST + s]);

  float h[DST];
  const size_t cb = (((size_t)n * NCH + c) * DIN + d) * DST;
#pragma unroll
  for (int s = 0; s < DST; ++s) h[s] = carry[cb + s];
  const float Dv = Dp[d];

  const size_t tok0 = (size_t)n * LSEQ + (size_t)c * CLEN;
#pragma unroll 2
  for (int i = 0; i < CLEN; ++i) {
    const size_t tok = tok0 + i;
    const float dtv = bf2fl(dtp[tok * DIN + d]);
    const float xcv = bf2fl(xcp[tok * DIN + d]);
    const float zv  = bf2fl(zp[tok * DIN + d]);
    const float bx = dtv * xcv;
    const float4* bmp = reinterpret_cast<const float4*>(Bm + tok * DST);
    const float4 b0 = bmp[0], b1 = bmp[1], b2 = bmp[2], b3 = bmp[3];
    const float bm[DST] = {b0.x,b0.y,b0.z,b0.w, b1.x,b1.y,b1.z,b1.w,
                           b2.x,b2.y,b2.z,b2.w, b3.x,b3.y,b3.z,b3.w};
    const float4* cmp = reinterpret_cast<const float4*>(Cm + tok * DST);
    const float4 c0 = cmp[0], c1 = cmp[1], c2 = cmp[2], c3 = cmp[3];
    const float cm[DST] = {c0.x,c0.y,c0.z,c0.w, c1.x,c1.y,c1.z,c1.w,
                           c2.x,c2.y,c2.z,c2.w, c3.x,c3.y,c3.z,c3.w};
    float y = Dv * xcv;
#pragma unroll
    for (int s = 0; s < DST; ++s) {
      const float a = __expf(dtv * Ar[s]);
      h[s] = fmaf(a, h[s], bx * bm[s]);
      y = fmaf(h[s], cm[s], y);
    }
    const float o = y * (zv * sigm(zv));
    yz[tok * DIN + d] = fl2bf(o);
  }
}

// K7: out_proj (128->64) + residual. thread=(n, l, half of 32 output channels).
__global__ __launch_bounds__(256) void k_outproj(
    const uint4* __restrict__ yz, const float* __restrict__ OW,
    const float* __restrict__ xin, float* __restrict__ out)
{
  const int l  = blockIdx.x * 256 + threadIdx.x;
  const int hf = blockIdx.y;
  const int n  = blockIdx.z;
  const size_t tok = (size_t)(n * LSEQ + l);

  float acc[32];
#pragma unroll
  for (int m = 0; m < 32; ++m) acc[m] = 0.f;

  const uint4* yp = yz + tok * 16;
  for (int q = 0; q < 16; ++q) {
    const uint4 r = yp[q];
    float f[8];
    unp8(r, f);
    const float* wbase = OW + (size_t)(hf * 32) * DIN + q * 8;
#pragma unroll
    for (int m = 0; m < 32; ++m) {
      const float* w = wbase + m * DIN;
#pragma unroll
      for (int e = 0; e < 8; ++e) acc[m] = fmaf(w[e], f[e], acc[m]);
    }
  }
#pragma unroll
  for (int m = 0; m < 32; ++m) {
    const size_t o = ((size_t)(n * DMODEL + hf * 32 + m)) * LSEQ + l;
    out[o] = xin[o] + acc[m];
  }
}

extern "C" void kernel_launch(void* const* d_in, const int* in_sizes, int n_in,
                              void* d_out, int out_size, void* d_ws, size_t ws_size,
                              hipStream_t stream)
{
  const float* x    = (const float*)d_in[0];
  const float* nw   = (const float*)d_in[1];
  const float* nb   = (const float*)d_in[2];
  const float* ipw  = (const float*)d_in[3];
  const float* cw   = (const float*)d_in[4];
  const float* cb   = (const float*)d_in[5];
  const float* xpw  = (const float*)d_in[6];
  const float* dpw  = (const float*)d_in[7];
  const float* dpb  = (const float*)d_in[8];
  const float* alog = (const float*)d_in[9];
  const float* dpar = (const float*)d_in[10];
  const float* opw  = (const float*)d_in[11];
  float* out = (float*)d_out;

  char* w = (char*)d_ws;
  const size_t tokch = (size_t)NSEQ * LSEQ * DIN;        // 9,437,184 elements
  unsigned short* xs = (unsigned short*)w; w += tokch * 2;
  unsigned short* zz = (unsigned short*)w; w += tokch * 2;
  unsigned short* xc = (unsigned short*)w; w += tokch * 2;
  unsigned short* dt = (unsigned short*)w; w += tokch * 2;
  float* Bm = (float*)w;    w += (size_t)NSEQ * LSEQ * DST * 4;
  float* Cm = (float*)w;    w += (size_t)NSEQ * LSEQ * DST * 4;
  float* P  = (float*)w;    w += (size_t)NSEQ * NCH * DIN * DST * 4;
  float* S  = (float*)w;    w += (size_t)NSEQ * NCH * DIN * DST * 4;
  float* carry = (float*)w; w += (size_t)NSEQ * NCH * DIN * DST * 4;
  unsigned short* yz = (unsigned short*)w; w += tokch * 2;

  k_ln_inproj<<<dim3(LSEQ / 256, 4, NSEQ), 256, 0, stream>>>(
      x, nw, nb, ipw, (unsigned*)xs, (unsigned*)zz);
  k_conv<<<dim3(LSEQ / 16, 1, NSEQ), 256, 0, stream>>>(
      (const uint4*)xs, cw, cb, (uint4*)xc);
  k_xproj<<<dim3((NSEQ * LSEQ) / 64), 256, 0, stream>>>(
      (const uint4*)xc, xpw, dpw, dpb, (unsigned*)dt, Bm, Cm);
  k_scanA<<<dim3(NCH, NSEQ), 128, 0, stream>>>(dt, xc, Bm, alog, P, S);
  k_comb<<<dim3((NSEQ * DIN * DST) / 256), 256, 0, stream>>>(P, S, carry);
  k_scanC<<<dim3(NCH, NSEQ), 128, 0, stream>>>(dt, xc, zz, Bm, Cm, alog, dpar, carry, yz);
  k_outproj<<<dim3(LSEQ / 256, 2, NSEQ), 256, 0, stream>>>(
      (const uint4*)yz, opw, x, out);
}

// Round 3
// 403.713 us; speedup vs baseline: 1.4642x; 1.1900x over previous
//
#include <hip/hip_runtime.h>
#include <hip/hip_bf16.h>

#define NSEQ 8
#define LSEQ 9216
#define DMODEL 64
#define DIN 128
#define DST 16
#define NCH 144
#define CLEN 64

typedef __attribute__((ext_vector_type(8))) short bf16x8;
typedef __attribute__((ext_vector_type(4))) float f32x4;

__device__ __forceinline__ float bf2fl(unsigned short b) {
  return __uint_as_float(((unsigned)b) << 16);
}
__device__ __forceinline__ unsigned short fl2bf(float f) {
  unsigned u = __float_as_uint(f);
  u += 0x7fffu + ((u >> 16) & 1u);
  return (unsigned short)(u >> 16);
}
__device__ __forceinline__ unsigned pk2(float lo, float hi) {
  return ((unsigned)fl2bf(hi) << 16) | (unsigned)fl2bf(lo);
}
__device__ __forceinline__ void unp8(const uint4 r, float* f) {
  f[0]=__uint_as_float(r.x<<16); f[1]=__uint_as_float(r.x&0xffff0000u);
  f[2]=__uint_as_float(r.y<<16); f[3]=__uint_as_float(r.y&0xffff0000u);
  f[4]=__uint_as_float(r.z<<16); f[5]=__uint_as_float(r.z&0xffff0000u);
  f[6]=__uint_as_float(r.w<<16); f[7]=__uint_as_float(r.w&0xffff0000u);
}
__device__ __forceinline__ float sigm(float x) {
  return __fdividef(1.f, 1.f + __expf(-x));
}

// K1: LayerNorm + in_proj. thread=(n, l, rowgroup of 64). writes xs (rows 0..127), z (128..255) as bf16.
__global__ __launch_bounds__(256) void k_ln_inproj(
    const float* __restrict__ x, const float* __restrict__ nw,
    const float* __restrict__ nb, const float* __restrict__ W,
    unsigned* __restrict__ xs, unsigned* __restrict__ zz)
{
  const int l  = blockIdx.x * 256 + threadIdx.x;
  const int rg = blockIdx.y;
  const int n  = blockIdx.z;

  const float* xp = x + ((size_t)n * DMODEL) * LSEQ + l;
  float v[DMODEL];
  float s0 = 0.f;
#pragma unroll
  for (int j = 0; j < DMODEL; ++j) { v[j] = xp[(size_t)j * LSEQ]; s0 += v[j]; }
  const float mu = s0 * (1.f / DMODEL);
  float s1 = 0.f;
#pragma unroll
  for (int j = 0; j < DMODEL; ++j) { float d = v[j] - mu; s1 += d * d; }
  const float rs = rsqrtf(s1 * (1.f / DMODEL) + 1e-6f);
#pragma unroll
  for (int j = 0; j < DMODEL; ++j) v[j] = (v[j] - mu) * rs * nw[j] + nb[j];

  const int r0 = rg * 64;
  unsigned* op = ((rg < 2) ? xs : zz) + ((size_t)(n * LSEQ + l)) * (DIN / 2) + (rg & 1) * 32;
  for (int rr = 0; rr < 64; rr += 4) {
    const float* w0 = W + (size_t)(r0 + rr) * DMODEL;
    float a0 = 0.f, a1 = 0.f, a2 = 0.f, a3 = 0.f;
#pragma unroll
    for (int j = 0; j < DMODEL; ++j) {
      const float vj = v[j];
      a0 = fmaf(w0[j], vj, a0);
      a1 = fmaf(w0[DMODEL + j], vj, a1);
      a2 = fmaf(w0[2 * DMODEL + j], vj, a2);
      a3 = fmaf(w0[3 * DMODEL + j], vj, a3);
    }
    uint2 pk;
    pk.x = pk2(a0, a1);
    pk.y = pk2(a2, a3);
    *reinterpret_cast<uint2*>(op + (rr >> 1)) = pk;
  }
}

// K2: depthwise causal conv (K=4) + SiLU. thread=(n, l, 8-channel group).
__global__ __launch_bounds__(256) void k_conv(
    const uint4* __restrict__ xs, const float* __restrict__ cw,
    const float* __restrict__ cb, uint4* __restrict__ xc)
{
  const int dg = threadIdx.x & 15;   // channel group (8 ch)
  const int dl = threadIdx.x >> 4;   // token within block
  const int l  = blockIdx.x * 16 + dl;
  const int n  = blockIdx.z;
  const int di0 = dg * 8;

  float acc[8];
#pragma unroll
  for (int e = 0; e < 8; ++e) acc[e] = cb[di0 + e];

  const long rowbase = (long)(n * LSEQ + l) * 16 + dg;  // uint4 index
#pragma unroll
  for (int k = 0; k < 4; ++k) {
    const int ls = l - 3 + k;
    if (ls >= 0) {
      const uint4 r = xs[rowbase + (long)(k - 3) * 16];
      float f[8];
      unp8(r, f);
#pragma unroll
      for (int e = 0; e < 8; ++e) acc[e] = fmaf(f[e], cw[(di0 + e) * 4 + k], acc[e]);
    }
  }
  unsigned o[4];
#pragma unroll
  for (int e = 0; e < 8; e += 2) {
    const float y0 = acc[e] * sigm(acc[e]);
    const float y1 = acc[e + 1] * sigm(acc[e + 1]);
    o[e >> 1] = pk2(y0, y1);
  }
  uint4 pkv; pkv.x = o[0]; pkv.y = o[1]; pkv.z = o[2]; pkv.w = o[3];
  xc[rowbase] = pkv;
}

// K3 prep: build combined x_proj weight W2 [160][128] bf16:
// rows 0..127  : (dt_proj_w @ XW[0:4]) combined dt weight
// rows 128..143: XW rows 4..19  (B)
// rows 144..159: XW rows 20..35 (C)
__global__ __launch_bounds__(256) void k_prep(
    const float* __restrict__ XW, const float* __restrict__ DW,
    unsigned short* __restrict__ W2)
{
  const int e = blockIdx.x * 256 + threadIdx.x;   // 0..20479
  const int d = e >> 7, k = e & 127;
  float v;
  if (d < 128) {
    v = 0.f;
#pragma unroll
    for (int r = 0; r < 4; ++r) v = fmaf(DW[d * 4 + r], XW[r * 128 + k], v);
  } else if (d < 144) {
    v = XW[(4 + (d - 128)) * 128 + k];
  } else {
    v = XW[(20 + (d - 144)) * 128 + k];
  }
  W2[e] = fl2bf(v);
}

// K3: fused x_proj + dt_proj + softplus as one bf16 MFMA GEMM.
// N=160 cols: 0..127 dt (pre-softplus), 128..143 B, 144..159 C. K=128.
// block = 4 waves; wave w owns 16 tokens (one M-tile); 10 col-tiles x 4 K-steps.
__global__ __launch_bounds__(256, 2) void k_xproj(
    const uint4* __restrict__ xc, const uint4* __restrict__ W2,
    const float* __restrict__ dtb,
    unsigned* __restrict__ dt, float* __restrict__ Bm, float* __restrict__ Cm)
{
  __shared__ unsigned short dts[64][132];
  __shared__ float bs[64][17];
  __shared__ float cs[64][17];

  const int tid   = threadIdx.x;
  const int lane  = tid & 63;
  const int w     = tid >> 6;
  const int col   = lane & 15;
  const int qw    = lane >> 4;
  const int tok0b = blockIdx.x * 64;
  const int tok0  = tok0b + w * 16;

  // B-fragments for all 10 col-tiles x 4 K-steps, straight from global (L2-hot).
  // W2 row-major [160][128] bf16 = 16 uint4 per row.
  bf16x8 bfr[10][4];
  {
    const uint4* wp = W2 + col * 16 + qw;
#pragma unroll
    for (int t = 0; t < 10; ++t)
#pragma unroll
      for (int s = 0; s < 4; ++s) {
        const uint4 u = wp[t * 256 + s * 4];
        bfr[t][s] = *(const bf16x8*)&u;
      }
  }

  f32x4 acc[10];
#pragma unroll
  for (int t = 0; t < 10; ++t) acc[t] = (f32x4){0.f, 0.f, 0.f, 0.f};

  {
    const uint4* ap = xc + ((size_t)(tok0 + col)) * 16 + qw;
#pragma unroll
    for (int s = 0; s < 4; ++s) {
      const uint4 u = ap[s * 4];
      const bf16x8 a = *(const bf16x8*)&u;
#pragma unroll
      for (int t = 0; t < 10; ++t)
        acc[t] = __builtin_amdgcn_mfma_f32_16x16x32_bf16(a, bfr[t][s], acc[t], 0, 0, 0);
    }
  }

  // epilogue: C/D layout col=lane&15, row=(lane>>4)*4+e
  const int tokl = w * 16 + qw * 4;
#pragma unroll
  for (int t = 0; t < 8; ++t) {
    const int d = t * 16 + col;
    const float bias = dtb[d];
#pragma unroll
    for (int e = 0; e < 4; ++e) {
      const float xv = acc[t][e] + bias;
      const float sp = fmaxf(xv, 0.f) + log1pf(__expf(-fabsf(xv)));
      dts[tokl + e][d] = fl2bf(sp);
    }
  }
#pragma unroll
  for (int e = 0; e < 4; ++e) bs[tokl + e][col] = acc[8][e];
#pragma unroll
  for (int e = 0; e < 4; ++e) cs[tokl + e][col] = acc[9][e];
  __syncthreads();

  // coalesced copy-out
  unsigned* __restrict__ dtg = dt + (size_t)tok0b * 64;   // 64 u32 per token
  const unsigned* dfl = (const unsigned*)&dts[0][0];      // row pitch 66 u32
#pragma unroll
  for (int i = 0; i < 16; ++i) {
    const int f = i * 256 + tid;       // 0..4095
    dtg[f] = dfl[(f >> 6) * 66 + (f & 63)];
  }
  float* __restrict__ bg = Bm + (size_t)tok0b * 16;
  float* __restrict__ cg = Cm + (size_t)tok0b * 16;
  const float* bfl = &bs[0][0];
  const float* cfl = &cs[0][0];
#pragma unroll
  for (int i = 0; i < 4; ++i) {
    const int f = i * 256 + tid;       // 0..1023
    bg[f] = bfl[f + (f >> 4)];
    cg[f] = cfl[f + (f >> 4)];
  }
}

// K4: scan pass A — per-chunk (prod a, local scan end). thread=(n, chunk, d).
__global__ __launch_bounds__(128) void k_scanA(
    const unsigned short* __restrict__ dtp, const unsigned short* __restrict__ xcp,
    const float* __restrict__ Bm, const float* __restrict__ A_log,
    float* __restrict__ P, float* __restrict__ S)
{
  const int d = threadIdx.x;
  const int c = blockIdx.x;
  const int n = blockIdx.y;

  float Ar[DST];
#pragma unroll
  for (int s = 0; s < DST; ++s) Ar[s] = -__expf(A_log[d * DST + s]);

  float p[DST], h[DST];
#pragma unroll
  for (int s = 0; s < DST; ++s) { p[s] = 1.f; h[s] = 0.f; }

  const size_t tok0 = (size_t)n * LSEQ + (size_t)c * CLEN;
#pragma unroll 2
  for (int i = 0; i < CLEN; ++i) {
    const size_t tok = tok0 + i;
    const float dtv = bf2fl(dtp[tok * DIN + d]);
    const float xcv = bf2fl(xcp[tok * DIN + d]);
    const float bx = dtv * xcv;
    const float4* bmp = reinterpret_cast<const float4*>(Bm + tok * DST);
    const float4 q0 = bmp[0], q1 = bmp[1], q2 = bmp[2], q3 = bmp[3];
    const float bm[DST] = {q0.x,q0.y,q0.z,q0.w, q1.x,q1.y,q1.z,q1.w,
                           q2.x,q2.y,q2.z,q2.w, q3.x,q3.y,q3.z,q3.w};
#pragma unroll
    for (int s = 0; s < DST; ++s) {
      const float a = __expf(dtv * Ar[s]);
      p[s] *= a;
      h[s] = fmaf(a, h[s], bx * bm[s]);
    }
  }
  const size_t ob = (((size_t)n * NCH + c) * DIN + d) * DST;
#pragma unroll
  for (int s = 0; s < DST; ++s) { P[ob + s] = p[s]; S[ob + s] = h[s]; }
}

// K5: sequential carry combine over chunks. thread = (n,d,s) chain.
__global__ __launch_bounds__(256) void k_comb(
    const float* __restrict__ P, const float* __restrict__ S, float* __restrict__ carry)
{
  const int t = blockIdx.x * 256 + threadIdx.x;  // 16384
  const int s = t & 15;
  const int d = (t >> 4) & 127;
  const int n = t >> 11;
  float h = 0.f;
  for (int c = 0; c < NCH; ++c) {
    const size_t idx = (((size_t)n * NCH + c) * DIN + d) * DST + s;
    carry[idx] = h;
    h = fmaf(P[idx], h, S[idx]);
  }
}

// K6: scan pass C — replay with carry-in, fuse y = C·h + D·xc, gate with silu(z). writes yz (bf16).
__global__ __launch_bounds__(128) void k_scanC(
    const unsigned short* __restrict__ dtp, const unsigned short* __restrict__ xcp,
    const unsigned short* __restrict__ zp,
    const float* __restrict__ Bm, const float* __restrict__ Cm,
    const float* __restrict__ A_log, const float* __restrict__ Dp,
    const float* __restrict__ carry, unsigned short* __restrict__ yz)
{
  const int d = threadIdx.x;
  const int c = blockIdx.x;
  const int n = blockIdx.y;

  float Ar[DST];
#pragma unroll
  for (int s = 0; s < DST; ++s) Ar[s] = -__expf(A_log[d * DST + s]);

  float h[DST];
  const size_t cb = (((size_t)n * NCH + c) * DIN + d) * DST;
#pragma unroll
  for (int s = 0; s < DST; ++s) h[s] = carry[cb + s];
  const float Dv = Dp[d];

  const size_t tok0 = (size_t)n * LSEQ + (size_t)c * CLEN;
#pragma unroll 2
  for (int i = 0; i < CLEN; ++i) {
    const size_t tok = tok0 + i;
    const float dtv = bf2fl(dtp[tok * DIN + d]);
    const float xcv = bf2fl(xcp[tok * DIN + d]);
    const float zv  = bf2fl(zp[tok * DIN + d]);
    const float bx = dtv * xcv;
    const float4* bmp = reinterpret_cast<const float4*>(Bm + tok * DST);
    const float4 b0 = bmp[0], b1 = bmp[1], b2 = bmp[2], b3 = bmp[3];
    const float bm[DST] = {b0.x,b0.y,b0.z,b0.w, b1.x,b1.y,b1.z,b1.w,
                           b2.x,b2.y,b2.z,b2.w, b3.x,b3.y,b3.z,b3.w};
    const float4* cmp = reinterpret_cast<const float4*>(Cm + tok * DST);
    const float4 c0 = cmp[0], c1 = cmp[1], c2 = cmp[2], c3 = cmp[3];
    const float cm[DST] = {c0.x,c0.y,c0.z,c0.w, c1.x,c1.y,c1.z,c1.w,
                           c2.x,c2.y,c2.z,c2.w, c3.x,c3.y,c3.z,c3.w};
    float y = Dv * xcv;
#pragma unroll
    for (int s = 0; s < DST; ++s) {
      const float a = __expf(dtv * Ar[s]);
      h[s] = fmaf(a, h[s], bx * bm[s]);
      y = fmaf(h[s], cm[s], y);
    }
    const float o = y * (zv * sigm(zv));
    yz[tok * DIN + d] = fl2bf(o);
  }
}

// K7: out_proj (128->64) + residual. thread=(n, l, half of 32 output channels).
__global__ __launch_bounds__(256) void k_outproj(
    const uint4* __restrict__ yz, const float* __restrict__ OW,
    const float* __restrict__ xin, float* __restrict__ out)
{
  const int l  = blockIdx.x * 256 + threadIdx.x;
  const int hf = blockIdx.y;
  const int n  = blockIdx.z;
  const size_t tok = (size_t)(n * LSEQ + l);

  float acc[32];
#pragma unroll
  for (int m = 0; m < 32; ++m) acc[m] = 0.f;

  const uint4* yp = yz + tok * 16;
  for (int q = 0; q < 16; ++q) {
    const uint4 r = yp[q];
    float f[8];
    unp8(r, f);
    const float* wbase = OW + (size_t)(hf * 32) * DIN + q * 8;
#pragma unroll
    for (int m = 0; m < 32; ++m) {
      const float* w = wbase + m * DIN;
#pragma unroll
      for (int e = 0; e < 8; ++e) acc[m] = fmaf(w[e], f[e], acc[m]);
    }
  }
#pragma unroll
  for (int m = 0; m < 32; ++m) {
    const size_t o = ((size_t)(n * DMODEL + hf * 32 + m)) * LSEQ + l;
    out[o] = xin[o] + acc[m];
  }
}

extern "C" void kernel_launch(void* const* d_in, const int* in_sizes, int n_in,
                              void* d_out, int out_size, void* d_ws, size_t ws_size,
                              hipStream_t stream)
{
  const float* x    = (const float*)d_in[0];
  const float* nw   = (const float*)d_in[1];
  const float* nb   = (const float*)d_in[2];
  const float* ipw  = (const float*)d_in[3];
  const float* cw   = (const float*)d_in[4];
  const float* cb   = (const float*)d_in[5];
  const float* xpw  = (const float*)d_in[6];
  const float* dpw  = (const float*)d_in[7];
  const float* dpb  = (const float*)d_in[8];
  const float* alog = (const float*)d_in[9];
  const float* dpar = (const float*)d_in[10];
  const float* opw  = (const float*)d_in[11];
  float* out = (float*)d_out;

  char* w = (char*)d_ws;
  const size_t tokch = (size_t)NSEQ * LSEQ * DIN;        // 9,437,184 elements
  unsigned short* xs = (unsigned short*)w; w += tokch * 2;
  unsigned short* zz = (unsigned short*)w; w += tokch * 2;
  unsigned short* xc = (unsigned short*)w; w += tokch * 2;
  unsigned short* dt = (unsigned short*)w; w += tokch * 2;
  float* Bm = (float*)w;    w += (size_t)NSEQ * LSEQ * DST * 4;
  float* Cm = (float*)w;    w += (size_t)NSEQ * LSEQ * DST * 4;
  float* P  = (float*)w;    w += (size_t)NSEQ * NCH * DIN * DST * 4;
  float* S  = (float*)w;    w += (size_t)NSEQ * NCH * DIN * DST * 4;
  float* carry = (float*)w; w += (size_t)NSEQ * NCH * DIN * DST * 4;
  unsigned short* yz = (unsigned short*)w; w += tokch * 2;
  unsigned short* W2 = (unsigned short*)w; w += (size_t)160 * 128 * 2;

  k_prep<<<dim3(80), 256, 0, stream>>>(xpw, dpw, W2);
  k_ln_inproj<<<dim3(LSEQ / 256, 4, NSEQ), 256, 0, stream>>>(
      x, nw, nb, ipw, (unsigned*)xs, (unsigned*)zz);
  k_conv<<<dim3(LSEQ / 16, 1, NSEQ), 256, 0, stream>>>(
      (const uint4*)xs, cw, cb, (uint4*)xc);
  k_xproj<<<dim3((NSEQ * LSEQ) / 64), 256, 0, stream>>>(
      (const uint4*)xc, (const uint4*)W2, dpb, (unsigned*)dt, Bm, Cm);
  k_scanA<<<dim3(NCH, NSEQ), 128, 0, stream>>>(dt, xc, Bm, alog, P, S);
  k_comb<<<dim3((NSEQ * DIN * DST) / 256), 256, 0, stream>>>(P, S, carry);
  k_scanC<<<dim3(NCH, NSEQ), 128, 0, stream>>>(dt, xc, zz, Bm, Cm, alog, dpar, carry, yz);
  k_outproj<<<dim3(LSEQ / 256, 2, NSEQ), 256, 0, stream>>>(
      (const uint4*)yz, opw, x, out);
}

// Round 4
// 328.568 us; speedup vs baseline: 1.7991x; 1.2287x over previous
//
#include <hip/hip_runtime.h>
#include <hip/hip_bf16.h>

#define NSEQ 8
#define LSEQ 9216
#define DMODEL 64
#define DIN 128
#define DST 16
#define NCH 144
#define CLEN 64

typedef __attribute__((ext_vector_type(8))) short bf16x8;
typedef __attribute__((ext_vector_type(4))) float f32x4;

__device__ __forceinline__ float bf2fl(unsigned short b) {
  return __uint_as_float(((unsigned)b) << 16);
}
__device__ __forceinline__ unsigned short fl2bf(float f) {
  unsigned u = __float_as_uint(f);
  u += 0x7fffu + ((u >> 16) & 1u);
  return (unsigned short)(u >> 16);
}
__device__ __forceinline__ unsigned pk2(float lo, float hi) {
  return ((unsigned)fl2bf(hi) << 16) | (unsigned)fl2bf(lo);
}
__device__ __forceinline__ void unp8(const uint4 r, float* f) {
  f[0]=__uint_as_float(r.x<<16); f[1]=__uint_as_float(r.x&0xffff0000u);
  f[2]=__uint_as_float(r.y<<16); f[3]=__uint_as_float(r.y&0xffff0000u);
  f[4]=__uint_as_float(r.z<<16); f[5]=__uint_as_float(r.z&0xffff0000u);
  f[6]=__uint_as_float(r.w<<16); f[7]=__uint_as_float(r.w&0xffff0000u);
}
__device__ __forceinline__ float sigm(float x) {
  return __fdividef(1.f, 1.f + __expf(-x));
}

// prep: W2 [160][128] bf16 (combined dt/B/C x_proj weight) + W1 [256][64] bf16 (in_proj).
__global__ __launch_bounds__(256) void k_prep(
    const float* __restrict__ XW, const float* __restrict__ DW,
    const float* __restrict__ IPW,
    unsigned short* __restrict__ W2, unsigned short* __restrict__ W1)
{
  const int e = blockIdx.x * 256 + threadIdx.x;
  if (e < 160 * 128) {
    const int d = e >> 7, k = e & 127;
    float v;
    if (d < 128) {
      v = 0.f;
#pragma unroll
      for (int r = 0; r < 4; ++r) v = fmaf(DW[d * 4 + r], XW[r * 128 + k], v);
    } else if (d < 144) {
      v = XW[(4 + (d - 128)) * 128 + k];
    } else {
      v = XW[(20 + (d - 144)) * 128 + k];
    }
    W2[e] = fl2bf(v);
  } else if (e < 160 * 128 + 256 * 64) {
    const int e2 = e - 160 * 128;
    W1[e2] = fl2bf(IPW[e2]);
  }
}

// K1: LayerNorm + in_proj as bf16 MFMA GEMM (M=64 tok/block, K=64, N=256).
// 4 waves; wave w owns output cols [64w,64w+64). xn staged in XOR-swizzled LDS.
__global__ __launch_bounds__(256, 2) void k_ln_inproj(
    const float* __restrict__ x, const float* __restrict__ nw,
    const float* __restrict__ nb, const uint4* __restrict__ W1,
    unsigned* __restrict__ xs, unsigned* __restrict__ zz)
{
  __shared__ char ldsA[64 * 128];
  __shared__ unsigned short xsb[64][132];
  __shared__ unsigned short zzb[64][132];

  const int tid   = threadIdx.x;
  const int lane  = tid & 63;
  const int w     = tid >> 6;
  const int col16 = lane & 15;
  const int qw    = lane >> 4;
  const int g0    = blockIdx.x * 64;
  const int n     = g0 / LSEQ;
  const int l     = (g0 % LSEQ) + lane;

  // phase 1: LN, lane = token (redundant across waves; wave w writes rows 16w..16w+15)
  {
    const float* xp = x + (size_t)n * DMODEL * LSEQ + l;
    float v[DMODEL];
    float s0 = 0.f;
#pragma unroll
    for (int j = 0; j < DMODEL; ++j) { v[j] = xp[(size_t)j * LSEQ]; s0 += v[j]; }
    const float mu = s0 * (1.f / DMODEL);
    float s1 = 0.f;
#pragma unroll
    for (int j = 0; j < DMODEL; ++j) { float d = v[j] - mu; s1 += d * d; }
    const float rs = rsqrtf(s1 * (1.f / DMODEL) + 1e-6f);
    if (qw == w) {
      const int row = lane;
#pragma unroll
      for (int s = 0; s < 8; ++s) {
        float f[8];
#pragma unroll
        for (int e = 0; e < 8; ++e)
          f[e] = (v[s * 8 + e] - mu) * rs * nw[s * 8 + e] + nb[s * 8 + e];
        uint4 pkv;
        pkv.x = pk2(f[0], f[1]); pkv.y = pk2(f[2], f[3]);
        pkv.z = pk2(f[4], f[5]); pkv.w = pk2(f[6], f[7]);
        *(uint4*)(ldsA + row * 128 + ((s ^ (row & 7)) << 4)) = pkv;
      }
    }
  }
  __syncthreads();

  // phase 2: MFMA. B-frags from global (L2-hot W1 [256][64] bf16 = 8 uint4/row).
  bf16x8 bfr[4][2];
  {
    const uint4* wp = W1 + (size_t)(w * 64 + col16) * 8 + qw;
#pragma unroll
    for (int t = 0; t < 4; ++t)
#pragma unroll
      for (int s = 0; s < 2; ++s) {
        const uint4 u = wp[t * 128 + s * 4];
        bfr[t][s] = *(const bf16x8*)&u;
      }
  }

  f32x4 acc[4][4];
#pragma unroll
  for (int m = 0; m < 4; ++m)
#pragma unroll
    for (int t = 0; t < 4; ++t) acc[m][t] = (f32x4){0.f, 0.f, 0.f, 0.f};

#pragma unroll
  for (int m = 0; m < 4; ++m) {
    const int row = m * 16 + col16;
#pragma unroll
    for (int s = 0; s < 2; ++s) {
      const int slot = qw + s * 4;
      const uint4 u = *(const uint4*)(ldsA + row * 128 + ((slot ^ (row & 7)) << 4));
      const bf16x8 a = *(const bf16x8*)&u;
#pragma unroll
      for (int t = 0; t < 4; ++t)
        acc[m][t] = __builtin_amdgcn_mfma_f32_16x16x32_bf16(a, bfr[t][s], acc[m][t], 0, 0, 0);
    }
  }

  // epilogue: D row = m*16 + qw*4 + e (token), col = w*64 + t*16 + col16
  {
    unsigned short (*obuf)[132] = (w < 2) ? xsb : zzb;
    const int cbase = (w & 1) * 64;
#pragma unroll
    for (int m = 0; m < 4; ++m)
#pragma unroll
      for (int t = 0; t < 4; ++t) {
        const int c = cbase + t * 16 + col16;
        const int tokl = m * 16 + qw * 4;
#pragma unroll
        for (int e = 0; e < 4; ++e)
          obuf[tokl + e][c] = fl2bf(acc[m][t][e]);
      }
  }
  __syncthreads();

  // coalesced copy-out: [64 tok][64 u32] flat per buffer
  unsigned* __restrict__ xg = xs + (size_t)g0 * 64;
  unsigned* __restrict__ zg = zz + (size_t)g0 * 64;
  const unsigned* xu = (const unsigned*)&xsb[0][0];
  const unsigned* zu = (const unsigned*)&zzb[0][0];
#pragma unroll
  for (int i = 0; i < 16; ++i) {
    const int f = i * 256 + tid;
    xg[f] = xu[(f >> 6) * 66 + (f & 63)];
    zg[f] = zu[(f >> 6) * 66 + (f & 63)];
  }
}

// K2: depthwise causal conv (K=4) + SiLU. thread=(n, l, 8-channel group).
__global__ __launch_bounds__(256) void k_conv(
    const uint4* __restrict__ xs, const float* __restrict__ cw,
    const float* __restrict__ cb, uint4* __restrict__ xc)
{
  const int dg = threadIdx.x & 15;   // channel group (8 ch)
  const int dl = threadIdx.x >> 4;   // token within block
  const int l  = blockIdx.x * 16 + dl;
  const int n  = blockIdx.z;
  const int di0 = dg * 8;

  float acc[8];
#pragma unroll
  for (int e = 0; e < 8; ++e) acc[e] = cb[di0 + e];

  const long rowbase = (long)(n * LSEQ + l) * 16 + dg;  // uint4 index
#pragma unroll
  for (int k = 0; k < 4; ++k) {
    const int ls = l - 3 + k;
    if (ls >= 0) {
      const uint4 r = xs[rowbase + (long)(k - 3) * 16];
      float f[8];
      unp8(r, f);
#pragma unroll
      for (int e = 0; e < 8; ++e) acc[e] = fmaf(f[e], cw[(di0 + e) * 4 + k], acc[e]);
    }
  }
  unsigned o[4];
#pragma unroll
  for (int e = 0; e < 8; e += 2) {
    const float y0 = acc[e] * sigm(acc[e]);
    const float y1 = acc[e + 1] * sigm(acc[e + 1]);
    o[e >> 1] = pk2(y0, y1);
  }
  uint4 pkv; pkv.x = o[0]; pkv.y = o[1]; pkv.z = o[2]; pkv.w = o[3];
  xc[rowbase] = pkv;
}

// K3: fused x_proj + dt_proj + softplus as one bf16 MFMA GEMM.
__global__ __launch_bounds__(256, 2) void k_xproj(
    const uint4* __restrict__ xc, const uint4* __restrict__ W2,
    const float* __restrict__ dtb,
    unsigned* __restrict__ dt, float* __restrict__ Bm, float* __restrict__ Cm)
{
  __shared__ unsigned short dts[64][132];
  __shared__ float bs[64][17];
  __shared__ float cs[64][17];

  const int tid   = threadIdx.x;
  const int lane  = tid & 63;
  const int w     = tid >> 6;
  const int col   = lane & 15;
  const int qw    = lane >> 4;
  const int tok0b = blockIdx.x * 64;
  const int tok0  = tok0b + w * 16;

  bf16x8 bfr[10][4];
  {
    const uint4* wp = W2 + col * 16 + qw;
#pragma unroll
    for (int t = 0; t < 10; ++t)
#pragma unroll
      for (int s = 0; s < 4; ++s) {
        const uint4 u = wp[t * 256 + s * 4];
        bfr[t][s] = *(const bf16x8*)&u;
      }
  }

  f32x4 acc[10];
#pragma unroll
  for (int t = 0; t < 10; ++t) acc[t] = (f32x4){0.f, 0.f, 0.f, 0.f};

  {
    const uint4* ap = xc + ((size_t)(tok0 + col)) * 16 + qw;
#pragma unroll
    for (int s = 0; s < 4; ++s) {
      const uint4 u = ap[s * 4];
      const bf16x8 a = *(const bf16x8*)&u;
#pragma unroll
      for (int t = 0; t < 10; ++t)
        acc[t] = __builtin_amdgcn_mfma_f32_16x16x32_bf16(a, bfr[t][s], acc[t], 0, 0, 0);
    }
  }

  const int tokl = w * 16 + qw * 4;
#pragma unroll
  for (int t = 0; t < 8; ++t) {
    const int d = t * 16 + col;
    const float bias = dtb[d];
#pragma unroll
    for (int e = 0; e < 4; ++e) {
      const float xv = acc[t][e] + bias;
      const float sp = fmaxf(xv, 0.f) + log1pf(__expf(-fabsf(xv)));
      dts[tokl + e][d] = fl2bf(sp);
    }
  }
#pragma unroll
  for (int e = 0; e < 4; ++e) bs[tokl + e][col] = acc[8][e];
#pragma unroll
  for (int e = 0; e < 4; ++e) cs[tokl + e][col] = acc[9][e];
  __syncthreads();

  unsigned* __restrict__ dtg = dt + (size_t)tok0b * 64;
  const unsigned* dfl = (const unsigned*)&dts[0][0];
#pragma unroll
  for (int i = 0; i < 16; ++i) {
    const int f = i * 256 + tid;
    dtg[f] = dfl[(f >> 6) * 66 + (f & 63)];
  }
  float* __restrict__ bg = Bm + (size_t)tok0b * 16;
  float* __restrict__ cg = Cm + (size_t)tok0b * 16;
  const float* bfl = &bs[0][0];
  const float* cfl = &cs[0][0];
#pragma unroll
  for (int i = 0; i < 4; ++i) {
    const int f = i * 256 + tid;
    bg[f] = bfl[f + (f >> 4)];
    cg[f] = cfl[f + (f >> 4)];
  }
}

// K4: scan pass A — per-chunk (prod a, local scan end). thread=(n, chunk, d).
__global__ __launch_bounds__(128) void k_scanA(
    const unsigned short* __restrict__ dtp, const unsigned short* __restrict__ xcp,
    const float* __restrict__ Bm, const float* __restrict__ A_log,
    float* __restrict__ P, float* __restrict__ S)
{
  const int d = threadIdx.x;
  const int c = blockIdx.x;
  const int n = blockIdx.y;

  float Ar[DST];
#pragma unroll
  for (int s = 0; s < DST; ++s) Ar[s] = -__expf(A_log[d * DST + s]);

  float p[DST], h[DST];
#pragma unroll
  for (int s = 0; s < DST; ++s) { p[s] = 1.f; h[s] = 0.f; }

  const size_t tok0 = (size_t)n * LSEQ + (size_t)c * CLEN;
#pragma unroll 2
  for (int i = 0; i < CLEN; ++i) {
    const size_t tok = tok0 + i;
    const float dtv = bf2fl(dtp[tok * DIN + d]);
    const float xcv = bf2fl(xcp[tok * DIN + d]);
    const float bx = dtv * xcv;
    const float4* bmp = reinterpret_cast<const float4*>(Bm + tok * DST);
    const float4 q0 = bmp[0], q1 = bmp[1], q2 = bmp[2], q3 = bmp[3];
    const float bm[DST] = {q0.x,q0.y,q0.z,q0.w, q1.x,q1.y,q1.z,q1.w,
                           q2.x,q2.y,q2.z,q2.w, q3.x,q3.y,q3.z,q3.w};
#pragma unroll
    for (int s = 0; s < DST; ++s) {
      const float a = __expf(dtv * Ar[s]);
      p[s] *= a;
      h[s] = fmaf(a, h[s], bx * bm[s]);
    }
  }
  const size_t ob = (((size_t)n * NCH + c) * DIN + d) * DST;
#pragma unroll
  for (int s = 0; s < DST; ++s) { P[ob + s] = p[s]; S[ob + s] = h[s]; }
}

// K5: sequential carry combine over chunks. thread = (n,d,s) chain.
__global__ __launch_bounds__(256) void k_comb(
    const float* __restrict__ P, const float* __restrict__ S, float* __restrict__ carry)
{
  const int t = blockIdx.x * 256 + threadIdx.x;  // 16384
  const int s = t & 15;
  const int d = (t >> 4) & 127;
  const int n = t >> 11;
  float h = 0.f;
  for (int c = 0; c < NCH; ++c) {
    const size_t idx = (((size_t)n * NCH + c) * DIN + d) * DST + s;
    carry[idx] = h;
    h = fmaf(P[idx], h, S[idx]);
  }
}

// K6: scan pass C — replay with carry-in, fuse y = C·h + D·xc, gate with silu(z). writes yz (bf16).
__global__ __launch_bounds__(128) void k_scanC(
    const unsigned short* __restrict__ dtp, const unsigned short* __restrict__ xcp,
    const unsigned short* __restrict__ zp,
    const float* __restrict__ Bm, const float* __restrict__ Cm,
    const float* __restrict__ A_log, const float* __restrict__ Dp,
    const float* __restrict__ carry, unsigned short* __restrict__ yz)
{
  const int d = threadIdx.x;
  const int c = blockIdx.x;
  const int n = blockIdx.y;

  float Ar[DST];
#pragma unroll
  for (int s = 0; s < DST; ++s) Ar[s] = -__expf(A_log[d * DST + s]);

  float h[DST];
  const size_t cb = (((size_t)n * NCH + c) * DIN + d) * DST;
#pragma unroll
  for (int s = 0; s < DST; ++s) h[s] = carry[cb + s];
  const float Dv = Dp[d];

  const size_t tok0 = (size_t)n * LSEQ + (size_t)c * CLEN;
#pragma unroll 2
  for (int i = 0; i < CLEN; ++i) {
    const size_t tok = tok0 + i;
    const float dtv = bf2fl(dtp[tok * DIN + d]);
    const float xcv = bf2fl(xcp[tok * DIN + d]);
    const float zv  = bf2fl(zp[tok * DIN + d]);
    const float bx = dtv * xcv;
    const float4* bmp = reinterpret_cast<const float4*>(Bm + tok * DST);
    const float4 b0 = bmp[0], b1 = bmp[1], b2 = bmp[2], b3 = bmp[3];
    const float bm[DST] = {b0.x,b0.y,b0.z,b0.w, b1.x,b1.y,b1.z,b1.w,
                           b2.x,b2.y,b2.z,b2.w, b3.x,b3.y,b3.z,b3.w};
    const float4* cmp = reinterpret_cast<const float4*>(Cm + tok * DST);
    const float4 c0 = cmp[0], c1 = cmp[1], c2 = cmp[2], c3 = cmp[3];
    const float cm[DST] = {c0.x,c0.y,c0.z,c0.w, c1.x,c1.y,c1.z,c1.w,
                           c2.x,c2.y,c2.z,c2.w, c3.x,c3.y,c3.z,c3.w};
    float y = Dv * xcv;
#pragma unroll
    for (int s = 0; s < DST; ++s) {
      const float a = __expf(dtv * Ar[s]);
      h[s] = fmaf(a, h[s], bx * bm[s]);
      y = fmaf(h[s], cm[s], y);
    }
    const float o = y * (zv * sigm(zv));
    yz[tok * DIN + d] = fl2bf(o);
  }
}

// K7: out_proj (128->64) + residual. thread=(n, l, half of 32 output channels).
__global__ __launch_bounds__(256) void k_outproj(
    const uint4* __restrict__ yz, const float* __restrict__ OW,
    const float* __restrict__ xin, float* __restrict__ out)
{
  const int l  = blockIdx.x * 256 + threadIdx.x;
  const int hf = blockIdx.y;
  const int n  = blockIdx.z;
  const size_t tok = (size_t)(n * LSEQ + l);

  float acc[32];
#pragma unroll
  for (int m = 0; m < 32; ++m) acc[m] = 0.f;

  const uint4* yp = yz + tok * 16;
  for (int q = 0; q < 16; ++q) {
    const uint4 r = yp[q];
    float f[8];
    unp8(r, f);
    const float* wbase = OW + (size_t)(hf * 32) * DIN + q * 8;
#pragma unroll
    for (int m = 0; m < 32; ++m) {
      const float* w = wbase + m * DIN;
#pragma unroll
      for (int e = 0; e < 8; ++e) acc[m] = fmaf(w[e], f[e], acc[m]);
    }
  }
#pragma unroll
  for (int m = 0; m < 32; ++m) {
    const size_t o = ((size_t)(n * DMODEL + hf * 32 + m)) * LSEQ + l;
    out[o] = xin[o] + acc[m];
  }
}

extern "C" void kernel_launch(void* const* d_in, const int* in_sizes, int n_in,
                              void* d_out, int out_size, void* d_ws, size_t ws_size,
                              hipStream_t stream)
{
  const float* x    = (const float*)d_in[0];
  const float* nw   = (const float*)d_in[1];
  const float* nb   = (const float*)d_in[2];
  const float* ipw  = (const float*)d_in[3];
  const float* cw   = (const float*)d_in[4];
  const float* cb   = (const float*)d_in[5];
  const float* xpw  = (const float*)d_in[6];
  const float* dpw  = (const float*)d_in[7];
  const float* dpb  = (const float*)d_in[8];
  const float* alog = (const float*)d_in[9];
  const float* dpar = (const float*)d_in[10];
  const float* opw  = (const float*)d_in[11];
  float* out = (float*)d_out;

  char* w = (char*)d_ws;
  const size_t tokch = (size_t)NSEQ * LSEQ * DIN;        // 9,437,184 elements
  unsigned short* xs = (unsigned short*)w; w += tokch * 2;
  unsigned short* zz = (unsigned short*)w; w += tokch * 2;
  unsigned short* xc = (unsigned short*)w; w += tokch * 2;
  unsigned short* dt = (unsigned short*)w; w += tokch * 2;
  float* Bm = (float*)w;    w += (size_t)NSEQ * LSEQ * DST * 4;
  float* Cm = (float*)w;    w += (size_t)NSEQ * LSEQ * DST * 4;
  float* P  = (float*)w;    w += (size_t)NSEQ * NCH * DIN * DST * 4;
  float* S  = (float*)w;    w += (size_t)NSEQ * NCH * DIN * DST * 4;
  float* carry = (float*)w; w += (size_t)NSEQ * NCH * DIN * DST * 4;
  unsigned short* yz = (unsigned short*)w; w += tokch * 2;
  unsigned short* W2 = (unsigned short*)w; w += (size_t)160 * 128 * 2;
  unsigned short* W1 = (unsigned short*)w; w += (size_t)256 * 64 * 2;

  k_prep<<<dim3(144), 256, 0, stream>>>(xpw, dpw, ipw, W2, W1);
  k_ln_inproj<<<dim3((NSEQ * LSEQ) / 64), 256, 0, stream>>>(
      x, nw, nb, (const uint4*)W1, (unsigned*)xs, (unsigned*)zz);
  k_conv<<<dim3(LSEQ / 16, 1, NSEQ), 256, 0, stream>>>(
      (const uint4*)xs, cw, cb, (uint4*)xc);
  k_xproj<<<dim3((NSEQ * LSEQ) / 64), 256, 0, stream>>>(
      (const uint4*)xc, (const uint4*)W2, dpb, (unsigned*)dt, Bm, Cm);
  k_scanA<<<dim3(NCH, NSEQ), 128, 0, stream>>>(dt, xc, Bm, alog, P, S);
  k_comb<<<dim3((NSEQ * DIN * DST) / 256), 256, 0, stream>>>(P, S, carry);
  k_scanC<<<dim3(NCH, NSEQ), 128, 0, stream>>>(dt, xc, zz, Bm, Cm, alog, dpar, carry, yz);
  k_outproj<<<dim3(LSEQ / 256, 2, NSEQ), 256, 0, stream>>>(
      (const uint4*)yz, opw, x, out);
}

// Round 5
// 298.093 us; speedup vs baseline: 1.9830x; 1.1022x over previous
//
#include <hip/hip_runtime.h>
#include <hip/hip_bf16.h>

#define NSEQ 8
#define LSEQ 9216
#define DMODEL 64
#define DIN 128
#define DST 16
#define NCH 144
#define CLEN 64

typedef __attribute__((ext_vector_type(8))) short bf16x8;
typedef __attribute__((ext_vector_type(4))) float f32x4;

__device__ __forceinline__ float bf2fl(unsigned short b) {
  return __uint_as_float(((unsigned)b) << 16);
}
__device__ __forceinline__ unsigned short fl2bf(float f) {
  unsigned u = __float_as_uint(f);
  u += 0x7fffu + ((u >> 16) & 1u);
  return (unsigned short)(u >> 16);
}
__device__ __forceinline__ unsigned pk2(float lo, float hi) {
  return ((unsigned)fl2bf(hi) << 16) | (unsigned)fl2bf(lo);
}
__device__ __forceinline__ void unp8(const uint4 r, float* f) {
  f[0]=__uint_as_float(r.x<<16); f[1]=__uint_as_float(r.x&0xffff0000u);
  f[2]=__uint_as_float(r.y<<16); f[3]=__uint_as_float(r.y&0xffff0000u);
  f[4]=__uint_as_float(r.z<<16); f[5]=__uint_as_float(r.z&0xffff0000u);
  f[6]=__uint_as_float(r.w<<16); f[7]=__uint_as_float(r.w&0xffff0000u);
}
__device__ __forceinline__ float sigm(float x) {
  return __fdividef(1.f, 1.f + __expf(-x));
}

// prep: W2 [160][128] bf16 (combined dt/B/C x_proj weight) + W1 [256][64] bf16 (in_proj).
__global__ __launch_bounds__(256) void k_prep(
    const float* __restrict__ XW, const float* __restrict__ DW,
    const float* __restrict__ IPW,
    unsigned short* __restrict__ W2, unsigned short* __restrict__ W1)
{
  const int e = blockIdx.x * 256 + threadIdx.x;
  if (e < 160 * 128) {
    const int d = e >> 7, k = e & 127;
    float v;
    if (d < 128) {
      v = 0.f;
#pragma unroll
      for (int r = 0; r < 4; ++r) v = fmaf(DW[d * 4 + r], XW[r * 128 + k], v);
    } else if (d < 144) {
      v = XW[(4 + (d - 128)) * 128 + k];
    } else {
      v = XW[(20 + (d - 144)) * 128 + k];
    }
    W2[e] = fl2bf(v);
  } else if (e < 160 * 128 + 256 * 64) {
    const int e2 = e - 160 * 128;
    W1[e2] = fl2bf(IPW[e2]);
  }
}

// K1: LayerNorm + in_proj as bf16 MFMA GEMM (M=64 tok/block, K=64, N=256).
// 4 waves; wave w owns output cols [64w,64w+64). xn staged in XOR-swizzled LDS.
__global__ __launch_bounds__(256, 2) void k_ln_inproj(
    const float* __restrict__ x, const float* __restrict__ nw,
    const float* __restrict__ nb, const uint4* __restrict__ W1,
    unsigned* __restrict__ xs, unsigned* __restrict__ zz)
{
  __shared__ char ldsA[64 * 128];
  __shared__ unsigned short xsb[64][132];
  __shared__ unsigned short zzb[64][132];

  const int tid   = threadIdx.x;
  const int lane  = tid & 63;
  const int w     = tid >> 6;
  const int col16 = lane & 15;
  const int qw    = lane >> 4;
  const int g0    = blockIdx.x * 64;
  const int n     = g0 / LSEQ;
  const int l     = (g0 % LSEQ) + lane;

  // phase 1: LN, lane = token (redundant across waves; wave w writes rows 16w..16w+15)
  {
    const float* xp = x + (size_t)n * DMODEL * LSEQ + l;
    float v[DMODEL];
    float s0 = 0.f;
#pragma unroll
    for (int j = 0; j < DMODEL; ++j) { v[j] = xp[(size_t)j * LSEQ]; s0 += v[j]; }
    const float mu = s0 * (1.f / DMODEL);
    float s1 = 0.f;
#pragma unroll
    for (int j = 0; j < DMODEL; ++j) { float d = v[j] - mu; s1 += d * d; }
    const float rs = rsqrtf(s1 * (1.f / DMODEL) + 1e-6f);
    if (qw == w) {
      const int row = lane;
#pragma unroll
      for (int s = 0; s < 8; ++s) {
        float f[8];
#pragma unroll
        for (int e = 0; e < 8; ++e)
          f[e] = (v[s * 8 + e] - mu) * rs * nw[s * 8 + e] + nb[s * 8 + e];
        uint4 pkv;
        pkv.x = pk2(f[0], f[1]); pkv.y = pk2(f[2], f[3]);
        pkv.z = pk2(f[4], f[5]); pkv.w = pk2(f[6], f[7]);
        *(uint4*)(ldsA + row * 128 + ((s ^ (row & 7)) << 4)) = pkv;
      }
    }
  }
  __syncthreads();

  // phase 2: MFMA. B-frags from global (L2-hot W1 [256][64] bf16 = 8 uint4/row).
  bf16x8 bfr[4][2];
  {
    const uint4* wp = W1 + (size_t)(w * 64 + col16) * 8 + qw;
#pragma unroll
    for (int t = 0; t < 4; ++t)
#pragma unroll
      for (int s = 0; s < 2; ++s) {
        const uint4 u = wp[t * 128 + s * 4];
        bfr[t][s] = *(const bf16x8*)&u;
      }
  }

  f32x4 acc[4][4];
#pragma unroll
  for (int m = 0; m < 4; ++m)
#pragma unroll
    for (int t = 0; t < 4; ++t) acc[m][t] = (f32x4){0.f, 0.f, 0.f, 0.f};

#pragma unroll
  for (int m = 0; m < 4; ++m) {
    const int row = m * 16 + col16;
#pragma unroll
    for (int s = 0; s < 2; ++s) {
      const int slot = qw + s * 4;
      const uint4 u = *(const uint4*)(ldsA + row * 128 + ((slot ^ (row & 7)) << 4));
      const bf16x8 a = *(const bf16x8*)&u;
#pragma unroll
      for (int t = 0; t < 4; ++t)
        acc[m][t] = __builtin_amdgcn_mfma_f32_16x16x32_bf16(a, bfr[t][s], acc[m][t], 0, 0, 0);
    }
  }

  // epilogue: D row = m*16 + qw*4 + e (token), col = w*64 + t*16 + col16
  {
    unsigned short (*obuf)[132] = (w < 2) ? xsb : zzb;
    const int cbase = (w & 1) * 64;
#pragma unroll
    for (int m = 0; m < 4; ++m)
#pragma unroll
      for (int t = 0; t < 4; ++t) {
        const int c = cbase + t * 16 + col16;
        const int tokl = m * 16 + qw * 4;
#pragma unroll
        for (int e = 0; e < 4; ++e)
          obuf[tokl + e][c] = fl2bf(acc[m][t][e]);
      }
  }
  __syncthreads();

  // coalesced copy-out: [64 tok][64 u32] flat per buffer
  unsigned* __restrict__ xg = xs + (size_t)g0 * 64;
  unsigned* __restrict__ zg = zz + (size_t)g0 * 64;
  const unsigned* xu = (const unsigned*)&xsb[0][0];
  const unsigned* zu = (const unsigned*)&zzb[0][0];
#pragma unroll
  for (int i = 0; i < 16; ++i) {
    const int f = i * 256 + tid;
    xg[f] = xu[(f >> 6) * 66 + (f & 63)];
    zg[f] = zu[(f >> 6) * 66 + (f & 63)];
  }
}

// K2: depthwise causal conv (K=4) + SiLU. thread=(n, l, 8-channel group).
__global__ __launch_bounds__(256) void k_conv(
    const uint4* __restrict__ xs, const float* __restrict__ cw,
    const float* __restrict__ cb, uint4* __restrict__ xc)
{
  const int dg = threadIdx.x & 15;   // channel group (8 ch)
  const int dl = threadIdx.x >> 4;   // token within block
  const int l  = blockIdx.x * 16 + dl;
  const int n  = blockIdx.z;
  const int di0 = dg * 8;

  float acc[8];
#pragma unroll
  for (int e = 0; e < 8; ++e) acc[e] = cb[di0 + e];

  const long rowbase = (long)(n * LSEQ + l) * 16 + dg;  // uint4 index
#pragma unroll
  for (int k = 0; k < 4; ++k) {
    const int ls = l - 3 + k;
    if (ls >= 0) {
      const uint4 r = xs[rowbase + (long)(k - 3) * 16];
      float f[8];
      unp8(r, f);
#pragma unroll
      for (int e = 0; e < 8; ++e) acc[e] = fmaf(f[e], cw[(di0 + e) * 4 + k], acc[e]);
    }
  }
  unsigned o[4];
#pragma unroll
  for (int e = 0; e < 8; e += 2) {
    const float y0 = acc[e] * sigm(acc[e]);
    const float y1 = acc[e + 1] * sigm(acc[e + 1]);
    o[e >> 1] = pk2(y0, y1);
  }
  uint4 pkv; pkv.x = o[0]; pkv.y = o[1]; pkv.z = o[2]; pkv.w = o[3];
  xc[rowbase] = pkv;
}

// K3: fused x_proj + dt_proj + softplus as one bf16 MFMA GEMM.
// W2 staged in XOR-swizzled LDS (40KB), reused for output staging after MFMA.
__global__ __launch_bounds__(256, 2) void k_xproj(
    const uint4* __restrict__ xc, const uint4* __restrict__ W2,
    const float* __restrict__ dtb,
    unsigned* __restrict__ dt, float* __restrict__ Bm, float* __restrict__ Cm)
{
  __shared__ char lds[40960];

  const int tid   = threadIdx.x;
  const int lane  = tid & 63;
  const int w     = tid >> 6;
  const int col   = lane & 15;
  const int qw    = lane >> 4;
  const int tok0b = blockIdx.x * 64;
  const int tok0  = tok0b + w * 16;

  // stage W2 [160 rows][16 uint4] into LDS with slot^(row&7) swizzle
#pragma unroll
  for (int i = 0; i < 10; ++i) {
    const int gi = i * 256 + tid;          // 0..2559
    const int row = gi >> 4, slot = gi & 15;
    const uint4 u = W2[gi];
    *(uint4*)(lds + row * 256 + ((slot ^ (row & 7)) << 4)) = u;
  }
  __syncthreads();

  f32x4 acc[10];
#pragma unroll
  for (int t = 0; t < 10; ++t) acc[t] = (f32x4){0.f, 0.f, 0.f, 0.f};

  {
    const uint4* ap = xc + ((size_t)(tok0 + col)) * 16 + qw;
#pragma unroll
    for (int s = 0; s < 4; ++s) {
      const uint4 ua = ap[s * 4];
      const bf16x8 a = *(const bf16x8*)&ua;
#pragma unroll
      for (int t = 0; t < 10; ++t) {
        const int row = t * 16 + col;
        const int slot = s * 4 + qw;
        const uint4 ub = *(const uint4*)(lds + row * 256 + ((slot ^ (row & 7)) << 4));
        const bf16x8 b = *(const bf16x8*)&ub;
        acc[t] = __builtin_amdgcn_mfma_f32_16x16x32_bf16(a, b, acc[t], 0, 0, 0);
      }
    }
  }
  __syncthreads();  // all waves done reading W2; reuse LDS for staging

  unsigned short (*dts)[132] = (unsigned short (*)[132])lds;          // 16896 B
  float (*bs)[17] = (float (*)[17])(lds + 16896);                     // 4352 B
  float (*cs)[17] = (float (*)[17])(lds + 16896 + 4352);              // 4352 B

  const int tokl = w * 16 + qw * 4;
#pragma unroll
  for (int t = 0; t < 8; ++t) {
    const int d = t * 16 + col;
    const float bias = dtb[d];
#pragma unroll
    for (int e = 0; e < 4; ++e) {
      const float xv = acc[t][e] + bias;
      const float sp = fmaxf(xv, 0.f) + __logf(1.f + __expf(-fabsf(xv)));
      dts[tokl + e][d] = fl2bf(sp);
    }
  }
#pragma unroll
  for (int e = 0; e < 4; ++e) bs[tokl + e][col] = acc[8][e];
#pragma unroll
  for (int e = 0; e < 4; ++e) cs[tokl + e][col] = acc[9][e];
  __syncthreads();

  unsigned* __restrict__ dtg = dt + (size_t)tok0b * 64;
  const unsigned* dfl = (const unsigned*)&dts[0][0];
#pragma unroll
  for (int i = 0; i < 16; ++i) {
    const int f = i * 256 + tid;
    dtg[f] = dfl[(f >> 6) * 66 + (f & 63)];
  }
  float* __restrict__ bg = Bm + (size_t)tok0b * 16;
  float* __restrict__ cg = Cm + (size_t)tok0b * 16;
  const float* bfl = &bs[0][0];
  const float* cfl = &cs[0][0];
#pragma unroll
  for (int i = 0; i < 4; ++i) {
    const int f = i * 256 + tid;
    bg[f] = bfl[f + (f >> 4)];
    cg[f] = cfl[f + (f >> 4)];
  }
}

// K4: scan pass A — per-chunk (prod a, local scan end). thread=(n, chunk, d).
__global__ __launch_bounds__(128) void k_scanA(
    const unsigned short* __restrict__ dtp, const unsigned short* __restrict__ xcp,
    const float* __restrict__ Bm, const float* __restrict__ A_log,
    float* __restrict__ P, float* __restrict__ S)
{
  const int d = threadIdx.x;
  const int c = blockIdx.x;
  const int n = blockIdx.y;

  float Ar[DST];
#pragma unroll
  for (int s = 0; s < DST; ++s) Ar[s] = -__expf(A_log[d * DST + s]);

  float p[DST], h[DST];
#pragma unroll
  for (int s = 0; s < DST; ++s) { p[s] = 1.f; h[s] = 0.f; }

  const size_t tok0 = (size_t)n * LSEQ + (size_t)c * CLEN;
#pragma unroll 2
  for (int i = 0; i < CLEN; ++i) {
    const size_t tok = tok0 + i;
    const float dtv = bf2fl(dtp[tok * DIN + d]);
    const float xcv = bf2fl(xcp[tok * DIN + d]);
    const float bx = dtv * xcv;
    const float4* bmp = reinterpret_cast<const float4*>(Bm + tok * DST);
    const float4 q0 = bmp[0], q1 = bmp[1], q2 = bmp[2], q3 = bmp[3];
    const float bm[DST] = {q0.x,q0.y,q0.z,q0.w, q1.x,q1.y,q1.z,q1.w,
                           q2.x,q2.y,q2.z,q2.w, q3.x,q3.y,q3.z,q3.w};
#pragma unroll
    for (int s = 0; s < DST; ++s) {
      const float a = __expf(dtv * Ar[s]);
      p[s] *= a;
      h[s] = fmaf(a, h[s], bx * bm[s]);
    }
  }
  const size_t ob = (((size_t)n * NCH + c) * DIN + d) * DST;
#pragma unroll
  for (int s = 0; s < DST; ++s) { P[ob + s] = p[s]; S[ob + s] = h[s]; }
}

// K5: sequential carry combine over chunks. thread = (n,d,s) chain.
__global__ __launch_bounds__(256) void k_comb(
    const float* __restrict__ P, const float* __restrict__ S, float* __restrict__ carry)
{
  const int t = blockIdx.x * 256 + threadIdx.x;  // 16384
  const int s = t & 15;
  const int d = (t >> 4) & 127;
  const int n = t >> 11;
  float h = 0.f;
  for (int c = 0; c < NCH; ++c) {
    const size_t idx = (((size_t)n * NCH + c) * DIN + d) * DST + s;
    carry[idx] = h;
    h = fmaf(P[idx], h, S[idx]);
  }
}

// K6: scan pass C — replay with carry-in, fuse y = C·h + D·xc, gate with silu(z). writes yz (bf16).
__global__ __launch_bounds__(128) void k_scanC(
    const unsigned short* __restrict__ dtp, const unsigned short* __restrict__ xcp,
    const unsigned short* __restrict__ zp,
    const float* __restrict__ Bm, const float* __restrict__ Cm,
    const float* __restrict__ A_log, const float* __restrict__ Dp,
    const float* __restrict__ carry, unsigned short* __restrict__ yz)
{
  const int d = threadIdx.x;
  const int c = blockIdx.x;
  const int n = blockIdx.y;

  float Ar[DST];
#pragma unroll
  for (int s = 0; s < DST; ++s) Ar[s] = -__expf(A_log[d * DST + s]);

  float h[DST];
  const size_t cb = (((size_t)n * NCH + c) * DIN + d) * DST;
#pragma unroll
  for (int s = 0; s < DST; ++s) h[s] = carry[cb + s];
  const float Dv = Dp[d];

  const size_t tok0 = (size_t)n * LSEQ + (size_t)c * CLEN;
#pragma unroll 2
  for (int i = 0; i < CLEN; ++i) {
    const size_t tok = tok0 + i;
    const float dtv = bf2fl(dtp[tok * DIN + d]);
    const float xcv = bf2fl(xcp[tok * DIN + d]);
    const float zv  = bf2fl(zp[tok * DIN + d]);
    const float bx = dtv * xcv;
    const float4* bmp = reinterpret_cast<const float4*>(Bm + tok * DST);
    const float4 b0 = bmp[0], b1 = bmp[1], b2 = bmp[2], b3 = bmp[3];
    const float bm[DST] = {b0.x,b0.y,b0.z,b0.w, b1.x,b1.y,b1.z,b1.w,
                           b2.x,b2.y,b2.z,b2.w, b3.x,b3.y,b3.z,b3.w};
    const float4* cmp = reinterpret_cast<const float4*>(Cm + tok * DST);
    const float4 c0 = cmp[0], c1 = cmp[1], c2 = cmp[2], c3 = cmp[3];
    const float cm[DST] = {c0.x,c0.y,c0.z,c0.w, c1.x,c1.y,c1.z,c1.w,
                           c2.x,c2.y,c2.z,c2.w, c3.x,c3.y,c3.z,c3.w};
    float y = Dv * xcv;
#pragma unroll
    for (int s = 0; s < DST; ++s) {
      const float a = __expf(dtv * Ar[s]);
      h[s] = fmaf(a, h[s], bx * bm[s]);
      y = fmaf(h[s], cm[s], y);
    }
    const float o = y * (zv * sigm(zv));
    yz[tok * DIN + d] = fl2bf(o);
  }
}

// K7: out_proj (128->64) + residual. thread=(n, l, half of 32 output channels).
__global__ __launch_bounds__(256) void k_outproj(
    const uint4* __restrict__ yz, const float* __restrict__ OW,
    const float* __restrict__ xin, float* __restrict__ out)
{
  const int l  = blockIdx.x * 256 + threadIdx.x;
  const int hf = blockIdx.y;
  const int n  = blockIdx.z;
  const size_t tok = (size_t)(n * LSEQ + l);

  float acc[32];
#pragma unroll
  for (int m = 0; m < 32; ++m) acc[m] = 0.f;

  const uint4* yp = yz + tok * 16;
  for (int q = 0; q < 16; ++q) {
    const uint4 r = yp[q];
    float f[8];
    unp8(r, f);
    const float* wbase = OW + (size_t)(hf * 32) * DIN + q * 8;
#pragma unroll
    for (int m = 0; m < 32; ++m) {
      const float* w = wbase + m * DIN;
#pragma unroll
      for (int e = 0; e < 8; ++e) acc[m] = fmaf(w[e], f[e], acc[m]);
    }
  }
#pragma unroll
  for (int m = 0; m < 32; ++m) {
    const size_t o = ((size_t)(n * DMODEL + hf * 32 + m)) * LSEQ + l;
    out[o] = xin[o] + acc[m];
  }
}

extern "C" void kernel_launch(void* const* d_in, const int* in_sizes, int n_in,
                              void* d_out, int out_size, void* d_ws, size_t ws_size,
                              hipStream_t stream)
{
  const float* x    = (const float*)d_in[0];
  const float* nw   = (const float*)d_in[1];
  const float* nb   = (const float*)d_in[2];
  const float* ipw  = (const float*)d_in[3];
  const float* cw   = (const float*)d_in[4];
  const float* cb   = (const float*)d_in[5];
  const float* xpw  = (const float*)d_in[6];
  const float* dpw  = (const float*)d_in[7];
  const float* dpb  = (const float*)d_in[8];
  const float* alog = (const float*)d_in[9];
  const float* dpar = (const float*)d_in[10];
  const float* opw  = (const float*)d_in[11];
  float* out = (float*)d_out;

  char* w = (char*)d_ws;
  const size_t tokch = (size_t)NSEQ * LSEQ * DIN;        // 9,437,184 elements
  unsigned short* xs = (unsigned short*)w; w += tokch * 2;
  unsigned short* zz = (unsigned short*)w; w += tokch * 2;
  unsigned short* xc = (unsigned short*)w; w += tokch * 2;
  unsigned short* dt = (unsigned short*)w; w += tokch * 2;
  float* Bm = (float*)w;    w += (size_t)NSEQ * LSEQ * DST * 4;
  float* Cm = (float*)w;    w += (size_t)NSEQ * LSEQ * DST * 4;
  float* P  = (float*)w;    w += (size_t)NSEQ * NCH * DIN * DST * 4;
  float* S  = (float*)w;    w += (size_t)NSEQ * NCH * DIN * DST * 4;
  float* carry = (float*)w; w += (size_t)NSEQ * NCH * DIN * DST * 4;
  unsigned short* yz = (unsigned short*)w; w += tokch * 2;
  unsigned short* W2 = (unsigned short*)w; w += (size_t)160 * 128 * 2;
  unsigned short* W1 = (unsigned short*)w; w += (size_t)256 * 64 * 2;

  k_prep<<<dim3(144), 256, 0, stream>>>(xpw, dpw, ipw, W2, W1);
  k_ln_inproj<<<dim3((NSEQ * LSEQ) / 64), 256, 0, stream>>>(
      x, nw, nb, (const uint4*)W1, (unsigned*)xs, (unsigned*)zz);
  k_conv<<<dim3(LSEQ / 16, 1, NSEQ), 256, 0, stream>>>(
      (const uint4*)xs, cw, cb, (uint4*)xc);
  k_xproj<<<dim3((NSEQ * LSEQ) / 64), 256, 0, stream>>>(
      (const uint4*)xc, (const uint4*)W2, dpb, (unsigned*)dt, Bm, Cm);
  k_scanA<<<dim3(NCH, NSEQ), 128, 0, stream>>>(dt, xc, Bm, alog, P, S);
  k_comb<<<dim3((NSEQ * DIN * DST) / 256), 256, 0, stream>>>(P, S, carry);
  k_scanC<<<dim3(NCH, NSEQ), 128, 0, stream>>>(dt, xc, zz, Bm, Cm, alog, dpar, carry, yz);
  k_outproj<<<dim3(LSEQ / 256, 2, NSEQ), 256, 0, stream>>>(
      (const uint4*)yz, opw, x, out);
}

// Round 6
// 241.865 us; speedup vs baseline: 2.4440x; 1.2325x over previous
//
#include <hip/hip_runtime.h>
#include <hip/hip_bf16.h>

#define NSEQ 8
#define LSEQ 9216
#define DMODEL 64
#define DIN 128
#define DST 16
#define NCH 144
#define CLEN 64

typedef __attribute__((ext_vector_type(8))) short bf16x8;
typedef __attribute__((ext_vector_type(4))) float f32x4;

__device__ __forceinline__ float bf2fl(unsigned short b) {
  return __uint_as_float(((unsigned)b) << 16);
}
__device__ __forceinline__ unsigned short fl2bf(float f) {
  unsigned u = __float_as_uint(f);
  u += 0x7fffu + ((u >> 16) & 1u);
  return (unsigned short)(u >> 16);
}
__device__ __forceinline__ unsigned pk2(float lo, float hi) {
  return ((unsigned)fl2bf(hi) << 16) | (unsigned)fl2bf(lo);
}
__device__ __forceinline__ void unp8(const uint4 r, float* f) {
  f[0]=__uint_as_float(r.x<<16); f[1]=__uint_as_float(r.x&0xffff0000u);
  f[2]=__uint_as_float(r.y<<16); f[3]=__uint_as_float(r.y&0xffff0000u);
  f[4]=__uint_as_float(r.z<<16); f[5]=__uint_as_float(r.z&0xffff0000u);
  f[6]=__uint_as_float(r.w<<16); f[7]=__uint_as_float(r.w&0xffff0000u);
}
__device__ __forceinline__ float sigm(float x) {
  return __fdividef(1.f, 1.f + __expf(-x));
}

// prep: W2 [160][128] (combined dt/B/C), W1 [256][64] (in_proj), W3 [64][128] (out_proj), all bf16.
__global__ __launch_bounds__(256) void k_prep(
    const float* __restrict__ XW, const float* __restrict__ DW,
    const float* __restrict__ IPW, const float* __restrict__ OPW,
    unsigned short* __restrict__ W2, unsigned short* __restrict__ W1,
    unsigned short* __restrict__ W3)
{
  const int e = blockIdx.x * 256 + threadIdx.x;
  if (e < 160 * 128) {
    const int d = e >> 7, k = e & 127;
    float v;
    if (d < 128) {
      v = 0.f;
#pragma unroll
      for (int r = 0; r < 4; ++r) v = fmaf(DW[d * 4 + r], XW[r * 128 + k], v);
    } else if (d < 144) {
      v = XW[(4 + (d - 128)) * 128 + k];
    } else {
      v = XW[(20 + (d - 144)) * 128 + k];
    }
    W2[e] = fl2bf(v);
  } else if (e < 160 * 128 + 256 * 64) {
    const int e2 = e - 160 * 128;
    W1[e2] = fl2bf(IPW[e2]);
  } else if (e < 160 * 128 + 256 * 64 + 64 * 128) {
    const int e3 = e - 160 * 128 - 256 * 64;
    W3[e3] = fl2bf(OPW[e3]);
  }
}

// K1: LayerNorm + in_proj as bf16 MFMA GEMM (M=64 tok/block, K=64, N=256).
__global__ __launch_bounds__(256, 2) void k_ln_inproj(
    const float* __restrict__ x, const float* __restrict__ nw,
    const float* __restrict__ nb, const uint4* __restrict__ W1,
    unsigned* __restrict__ xs, unsigned* __restrict__ zz)
{
  __shared__ char ldsA[64 * 128];
  __shared__ unsigned short xsb[64][132];
  __shared__ unsigned short zzb[64][132];

  const int tid   = threadIdx.x;
  const int lane  = tid & 63;
  const int w     = tid >> 6;
  const int col16 = lane & 15;
  const int qw    = lane >> 4;
  const int g0    = blockIdx.x * 64;
  const int n     = g0 / LSEQ;
  const int l     = (g0 % LSEQ) + lane;

  {
    const float* xp = x + (size_t)n * DMODEL * LSEQ + l;
    float v[DMODEL];
    float s0 = 0.f;
#pragma unroll
    for (int j = 0; j < DMODEL; ++j) { v[j] = xp[(size_t)j * LSEQ]; s0 += v[j]; }
    const float mu = s0 * (1.f / DMODEL);
    float s1 = 0.f;
#pragma unroll
    for (int j = 0; j < DMODEL; ++j) { float d = v[j] - mu; s1 += d * d; }
    const float rs = rsqrtf(s1 * (1.f / DMODEL) + 1e-6f);
    if (qw == w) {
      const int row = lane;
#pragma unroll
      for (int s = 0; s < 8; ++s) {
        float f[8];
#pragma unroll
        for (int e = 0; e < 8; ++e)
          f[e] = (v[s * 8 + e] - mu) * rs * nw[s * 8 + e] + nb[s * 8 + e];
        uint4 pkv;
        pkv.x = pk2(f[0], f[1]); pkv.y = pk2(f[2], f[3]);
        pkv.z = pk2(f[4], f[5]); pkv.w = pk2(f[6], f[7]);
        *(uint4*)(ldsA + row * 128 + ((s ^ (row & 7)) << 4)) = pkv;
      }
    }
  }
  __syncthreads();

  bf16x8 bfr[4][2];
  {
    const uint4* wp = W1 + (size_t)(w * 64 + col16) * 8 + qw;
#pragma unroll
    for (int t = 0; t < 4; ++t)
#pragma unroll
      for (int s = 0; s < 2; ++s) {
        const uint4 u = wp[t * 128 + s * 4];
        bfr[t][s] = *(const bf16x8*)&u;
      }
  }

  f32x4 acc[4][4];
#pragma unroll
  for (int m = 0; m < 4; ++m)
#pragma unroll
    for (int t = 0; t < 4; ++t) acc[m][t] = (f32x4){0.f, 0.f, 0.f, 0.f};

#pragma unroll
  for (int m = 0; m < 4; ++m) {
    const int row = m * 16 + col16;
#pragma unroll
    for (int s = 0; s < 2; ++s) {
      const int slot = qw + s * 4;
      const uint4 u = *(const uint4*)(ldsA + row * 128 + ((slot ^ (row & 7)) << 4));
      const bf16x8 a = *(const bf16x8*)&u;
#pragma unroll
      for (int t = 0; t < 4; ++t)
        acc[m][t] = __builtin_amdgcn_mfma_f32_16x16x32_bf16(a, bfr[t][s], acc[m][t], 0, 0, 0);
    }
  }

  {
    unsigned short (*obuf)[132] = (w < 2) ? xsb : zzb;
    const int cbase = (w & 1) * 64;
#pragma unroll
    for (int m = 0; m < 4; ++m)
#pragma unroll
      for (int t = 0; t < 4; ++t) {
        const int c = cbase + t * 16 + col16;
        const int tokl = m * 16 + qw * 4;
#pragma unroll
        for (int e = 0; e < 4; ++e)
          obuf[tokl + e][c] = fl2bf(acc[m][t][e]);
      }
  }
  __syncthreads();

  unsigned* __restrict__ xg = xs + (size_t)g0 * 64;
  unsigned* __restrict__ zg = zz + (size_t)g0 * 64;
  const unsigned* xu = (const unsigned*)&xsb[0][0];
  const unsigned* zu = (const unsigned*)&zzb[0][0];
#pragma unroll
  for (int i = 0; i < 16; ++i) {
    const int f = i * 256 + tid;
    xg[f] = xu[(f >> 6) * 66 + (f & 63)];
    zg[f] = zu[(f >> 6) * 66 + (f & 63)];
  }
}

// K2: depthwise causal conv (K=4) + SiLU. thread=(n, l, 8-channel group).
__global__ __launch_bounds__(256) void k_conv(
    const uint4* __restrict__ xs, const float* __restrict__ cw,
    const float* __restrict__ cb, uint4* __restrict__ xc)
{
  const int dg = threadIdx.x & 15;   // channel group (8 ch)
  const int dl = threadIdx.x >> 4;   // token within block
  const int l  = blockIdx.x * 16 + dl;
  const int n  = blockIdx.z;
  const int di0 = dg * 8;

  float acc[8];
#pragma unroll
  for (int e = 0; e < 8; ++e) acc[e] = cb[di0 + e];

  const long rowbase = (long)(n * LSEQ + l) * 16 + dg;  // uint4 index
#pragma unroll
  for (int k = 0; k < 4; ++k) {
    const int ls = l - 3 + k;
    if (ls >= 0) {
      const uint4 r = xs[rowbase + (long)(k - 3) * 16];
      float f[8];
      unp8(r, f);
#pragma unroll
      for (int e = 0; e < 8; ++e) acc[e] = fmaf(f[e], cw[(di0 + e) * 4 + k], acc[e]);
    }
  }
  unsigned o[4];
#pragma unroll
  for (int e = 0; e < 8; e += 2) {
    const float y0 = acc[e] * sigm(acc[e]);
    const float y1 = acc[e + 1] * sigm(acc[e + 1]);
    o[e >> 1] = pk2(y0, y1);
  }
  uint4 pkv; pkv.x = o[0]; pkv.y = o[1]; pkv.z = o[2]; pkv.w = o[3];
  xc[rowbase] = pkv;
}

// K3: fused x_proj + dt_proj + softplus as one bf16 MFMA GEMM.
__global__ __launch_bounds__(256, 2) void k_xproj(
    const uint4* __restrict__ xc, const uint4* __restrict__ W2,
    const float* __restrict__ dtb,
    unsigned* __restrict__ dt, float* __restrict__ Bm, float* __restrict__ Cm)
{
  __shared__ char lds[40960];

  const int tid   = threadIdx.x;
  const int lane  = tid & 63;
  const int w     = tid >> 6;
  const int col   = lane & 15;
  const int qw    = lane >> 4;
  const int tok0b = blockIdx.x * 64;
  const int tok0  = tok0b + w * 16;

#pragma unroll
  for (int i = 0; i < 10; ++i) {
    const int gi = i * 256 + tid;
    const int row = gi >> 4, slot = gi & 15;
    const uint4 u = W2[gi];
    *(uint4*)(lds + row * 256 + ((slot ^ (row & 7)) << 4)) = u;
  }
  __syncthreads();

  f32x4 acc[10];
#pragma unroll
  for (int t = 0; t < 10; ++t) acc[t] = (f32x4){0.f, 0.f, 0.f, 0.f};

  {
    const uint4* ap = xc + ((size_t)(tok0 + col)) * 16 + qw;
#pragma unroll
    for (int s = 0; s < 4; ++s) {
      const uint4 ua = ap[s * 4];
      const bf16x8 a = *(const bf16x8*)&ua;
#pragma unroll
      for (int t = 0; t < 10; ++t) {
        const int row = t * 16 + col;
        const int slot = s * 4 + qw;
        const uint4 ub = *(const uint4*)(lds + row * 256 + ((slot ^ (row & 7)) << 4));
        const bf16x8 b = *(const bf16x8*)&ub;
        acc[t] = __builtin_amdgcn_mfma_f32_16x16x32_bf16(a, b, acc[t], 0, 0, 0);
      }
    }
  }
  __syncthreads();

  unsigned short (*dts)[132] = (unsigned short (*)[132])lds;
  float (*bs)[17] = (float (*)[17])(lds + 16896);
  float (*cs)[17] = (float (*)[17])(lds + 16896 + 4352);

  const int tokl = w * 16 + qw * 4;
#pragma unroll
  for (int t = 0; t < 8; ++t) {
    const int d = t * 16 + col;
    const float bias = dtb[d];
#pragma unroll
    for (int e = 0; e < 4; ++e) {
      const float xv = acc[t][e] + bias;
      const float sp = fmaxf(xv, 0.f) + __logf(1.f + __expf(-fabsf(xv)));
      dts[tokl + e][d] = fl2bf(sp);
    }
  }
#pragma unroll
  for (int e = 0; e < 4; ++e) bs[tokl + e][col] = acc[8][e];
#pragma unroll
  for (int e = 0; e < 4; ++e) cs[tokl + e][col] = acc[9][e];
  __syncthreads();

  unsigned* __restrict__ dtg = dt + (size_t)tok0b * 64;
  const unsigned* dfl = (const unsigned*)&dts[0][0];
#pragma unroll
  for (int i = 0; i < 16; ++i) {
    const int f = i * 256 + tid;
    dtg[f] = dfl[(f >> 6) * 66 + (f & 63)];
  }
  float* __restrict__ bg = Bm + (size_t)tok0b * 16;
  float* __restrict__ cg = Cm + (size_t)tok0b * 16;
  const float* bfl = &bs[0][0];
  const float* cfl = &cs[0][0];
#pragma unroll
  for (int i = 0; i < 4; ++i) {
    const int f = i * 256 + tid;
    bg[f] = bfl[f + (f >> 4)];
    cg[f] = cfl[f + (f >> 4)];
  }
}

// K4: scan pass A — per-chunk (prod a, local scan end). thread=(n, chunk, d).
__global__ __launch_bounds__(128) void k_scanA(
    const unsigned short* __restrict__ dtp, const unsigned short* __restrict__ xcp,
    const float* __restrict__ Bm, const float* __restrict__ A_log,
    float* __restrict__ P, float* __restrict__ S)
{
  const int d = threadIdx.x;
  const int c = blockIdx.x;
  const int n = blockIdx.y;

  float Ar[DST];
#pragma unroll
  for (int s = 0; s < DST; ++s) Ar[s] = -__expf(A_log[d * DST + s]);

  float p[DST], h[DST];
#pragma unroll
  for (int s = 0; s < DST; ++s) { p[s] = 1.f; h[s] = 0.f; }

  const size_t tok0 = (size_t)n * LSEQ + (size_t)c * CLEN;
#pragma unroll 2
  for (int i = 0; i < CLEN; ++i) {
    const size_t tok = tok0 + i;
    const float dtv = bf2fl(dtp[tok * DIN + d]);
    const float xcv = bf2fl(xcp[tok * DIN + d]);
    const float bx = dtv * xcv;
    const float4* bmp = reinterpret_cast<const float4*>(Bm + tok * DST);
    const float4 q0 = bmp[0], q1 = bmp[1], q2 = bmp[2], q3 = bmp[3];
    const float bm[DST] = {q0.x,q0.y,q0.z,q0.w, q1.x,q1.y,q1.z,q1.w,
                           q2.x,q2.y,q2.z,q2.w, q3.x,q3.y,q3.z,q3.w};
#pragma unroll
    for (int s = 0; s < DST; ++s) {
      const float a = __expf(dtv * Ar[s]);
      p[s] *= a;
      h[s] = fmaf(a, h[s], bx * bm[s]);
    }
  }
  const size_t ob = (((size_t)n * NCH + c) * DIN + d) * DST;
#pragma unroll
  for (int s = 0; s < DST; ++s) { P[ob + s] = p[s]; S[ob + s] = h[s]; }
}

// K5: sequential carry combine over chunks. thread = (n,d,s) chain.
__global__ __launch_bounds__(256) void k_comb(
    const float* __restrict__ P, const float* __restrict__ S, float* __restrict__ carry)
{
  const int t = blockIdx.x * 256 + threadIdx.x;  // 16384
  const int s = t & 15;
  const int d = (t >> 4) & 127;
  const int n = t >> 11;
  float h = 0.f;
  for (int c = 0; c < NCH; ++c) {
    const size_t idx = (((size_t)n * NCH + c) * DIN + d) * DST + s;
    carry[idx] = h;
    h = fmaf(P[idx], h, S[idx]);
  }
}

// K6: scan pass C — replay with carry-in, fuse y = C·h + D·xc, gate with silu(z). writes yz (bf16).
__global__ __launch_bounds__(128) void k_scanC(
    const unsigned short* __restrict__ dtp, const unsigned short* __restrict__ xcp,
    const unsigned short* __restrict__ zp,
    const float* __restrict__ Bm, const float* __restrict__ Cm,
    const float* __restrict__ A_log, const float* __restrict__ Dp,
    const float* __restrict__ carry, unsigned short* __restrict__ yz)
{
  const int d = threadIdx.x;
  const int c = blockIdx.x;
  const int n = blockIdx.y;

  float Ar[DST];
#pragma unroll
  for (int s = 0; s < DST; ++s) Ar[s] = -__expf(A_log[d * DST + s]);

  float h[DST];
  const size_t cb = (((size_t)n * NCH + c) * DIN + d) * DST;
#pragma unroll
  for (int s = 0; s < DST; ++s) h[s] = carry[cb + s];
  const float Dv = Dp[d];

  const size_t tok0 = (size_t)n * LSEQ + (size_t)c * CLEN;
#pragma unroll 2
  for (int i = 0; i < CLEN; ++i) {
    const size_t tok = tok0 + i;
    const float dtv = bf2fl(dtp[tok * DIN + d]);
    const float xcv = bf2fl(xcp[tok * DIN + d]);
    const float zv  = bf2fl(zp[tok * DIN + d]);
    const float bx = dtv * xcv;
    const float4* bmp = reinterpret_cast<const float4*>(Bm + tok * DST);
    const float4 b0 = bmp[0], b1 = bmp[1], b2 = bmp[2], b3 = bmp[3];
    const float bm[DST] = {b0.x,b0.y,b0.z,b0.w, b1.x,b1.y,b1.z,b1.w,
                           b2.x,b2.y,b2.z,b2.w, b3.x,b3.y,b3.z,b3.w};
    const float4* cmp = reinterpret_cast<const float4*>(Cm + tok * DST);
    const float4 c0 = cmp[0], c1 = cmp[1], c2 = cmp[2], c3 = cmp[3];
    const float cm[DST] = {c0.x,c0.y,c0.z,c0.w, c1.x,c1.y,c1.z,c1.w,
                           c2.x,c2.y,c2.z,c2.w, c3.x,c3.y,c3.z,c3.w};
    float y = Dv * xcv;
#pragma unroll
    for (int s = 0; s < DST; ++s) {
      const float a = __expf(dtv * Ar[s]);
      h[s] = fmaf(a, h[s], bx * bm[s]);
      y = fmaf(h[s], cm[s], y);
    }
    const float o = y * (zv * sigm(zv));
    yz[tok * DIN + d] = fl2bf(o);
  }
}

// K7: out_proj (128->64) + residual as bf16 MFMA GEMM + coalesced epilogue.
__global__ __launch_bounds__(256, 4) void k_outproj(
    const uint4* __restrict__ yz, const uint4* __restrict__ W3,
    const float* __restrict__ xin, float* __restrict__ out)
{
  __shared__ char lds[16896];   // W3 staging (16384 B), then sbuf[64][66] f32 (16896 B)

  const int tid  = threadIdx.x;
  const int lane = tid & 63;
  const int w    = tid >> 6;
  const int col  = lane & 15;
  const int qw   = lane >> 4;
  const int g0   = blockIdx.x * 64;
  const int n    = g0 / LSEQ;
  const int l0   = g0 % LSEQ;

  // stage W3 [64 rows][16 uint4] swizzled
#pragma unroll
  for (int i = 0; i < 4; ++i) {
    const int gi = i * 256 + tid;       // 0..1023
    const int row = gi >> 4, slot = gi & 15;
    const uint4 u = W3[gi];
    *(uint4*)(lds + row * 256 + ((slot ^ (row & 7)) << 4)) = u;
  }
  __syncthreads();

  f32x4 acc[4];
#pragma unroll
  for (int t = 0; t < 4; ++t) acc[t] = (f32x4){0.f, 0.f, 0.f, 0.f};

  {
    const uint4* ap = yz + ((size_t)(g0 + w * 16 + col)) * 16 + qw;
#pragma unroll
    for (int s = 0; s < 4; ++s) {
      const uint4 ua = ap[s * 4];
      const bf16x8 a = *(const bf16x8*)&ua;
#pragma unroll
      for (int t = 0; t < 4; ++t) {
        const int row = t * 16 + col;
        const int slot = s * 4 + qw;
        const uint4 ub = *(const uint4*)(lds + row * 256 + ((slot ^ (row & 7)) << 4));
        const bf16x8 b = *(const bf16x8*)&ub;
        acc[t] = __builtin_amdgcn_mfma_f32_16x16x32_bf16(a, b, acc[t], 0, 0, 0);
      }
    }
  }
  __syncthreads();

  float (*sbuf)[66] = (float (*)[66])lds;
  const int tokl = w * 16 + qw * 4;
#pragma unroll
  for (int t = 0; t < 4; ++t) {
    const int c = t * 16 + col;
#pragma unroll
    for (int e = 0; e < 4; ++e) sbuf[tokl + e][c] = acc[t][e];
  }
  __syncthreads();

  // channel-major copy-out with residual: 256B coalesced reads/writes per wave
#pragma unroll
  for (int i = 0; i < 16; ++i) {
    const int f = i * 256 + tid;         // 0..4095
    const int ch = f >> 6, tk = f & 63;
    const size_t g = ((size_t)(n * DMODEL + ch)) * LSEQ + l0 + tk;
    out[g] = xin[g] + sbuf[tk][ch];
  }
}

extern "C" void kernel_launch(void* const* d_in, const int* in_sizes, int n_in,
                              void* d_out, int out_size, void* d_ws, size_t ws_size,
                              hipStream_t stream)
{
  const float* x    = (const float*)d_in[0];
  const float* nw   = (const float*)d_in[1];
  const float* nb   = (const float*)d_in[2];
  const float* ipw  = (const float*)d_in[3];
  const float* cw   = (const float*)d_in[4];
  const float* cb   = (const float*)d_in[5];
  const float* xpw  = (const float*)d_in[6];
  const float* dpw  = (const float*)d_in[7];
  const float* dpb  = (const float*)d_in[8];
  const float* alog = (const float*)d_in[9];
  const float* dpar = (const float*)d_in[10];
  const float* opw  = (const float*)d_in[11];
  float* out = (float*)d_out;

  char* w = (char*)d_ws;
  const size_t tokch = (size_t)NSEQ * LSEQ * DIN;        // 9,437,184 elements
  unsigned short* xs = (unsigned short*)w; w += tokch * 2;
  unsigned short* zz = (unsigned short*)w; w += tokch * 2;
  unsigned short* xc = (unsigned short*)w; w += tokch * 2;
  unsigned short* dt = (unsigned short*)w; w += tokch * 2;
  float* Bm = (float*)w;    w += (size_t)NSEQ * LSEQ * DST * 4;
  float* Cm = (float*)w;    w += (size_t)NSEQ * LSEQ * DST * 4;
  float* P  = (float*)w;    w += (size_t)NSEQ * NCH * DIN * DST * 4;
  float* S  = (float*)w;    w += (size_t)NSEQ * NCH * DIN * DST * 4;
  float* carry = (float*)w; w += (size_t)NSEQ * NCH * DIN * DST * 4;
  unsigned short* yz = (unsigned short*)w; w += tokch * 2;
  unsigned short* W2 = (unsigned short*)w; w += (size_t)160 * 128 * 2;
  unsigned short* W1 = (unsigned short*)w; w += (size_t)256 * 64 * 2;
  unsigned short* W3 = (unsigned short*)w; w += (size_t)64 * 128 * 2;

  k_prep<<<dim3(176), 256, 0, stream>>>(xpw, dpw, ipw, opw, W2, W1, W3);
  k_ln_inproj<<<dim3((NSEQ * LSEQ) / 64), 256, 0, stream>>>(
      x, nw, nb, (const uint4*)W1, (unsigned*)xs, (unsigned*)zz);
  k_conv<<<dim3(LSEQ / 16, 1, NSEQ), 256, 0, stream>>>(
      (const uint4*)xs, cw, cb, (uint4*)xc);
  k_xproj<<<dim3((NSEQ * LSEQ) / 64), 256, 0, stream>>>(
      (const uint4*)xc, (const uint4*)W2, dpb, (unsigned*)dt, Bm, Cm);
  k_scanA<<<dim3(NCH, NSEQ), 128, 0, stream>>>(dt, xc, Bm, alog, P, S);
  k_comb<<<dim3((NSEQ * DIN * DST) / 256), 256, 0, stream>>>(P, S, carry);
  k_scanC<<<dim3(NCH, NSEQ), 128, 0, stream>>>(dt, xc, zz, Bm, Cm, alog, dpar, carry, yz);
  k_outproj<<<dim3((NSEQ * LSEQ) / 64), 256, 0, stream>>>(
      (const uint4*)yz, (const uint4*)W3, x, out);
}

// Round 7
// 188.719 us; speedup vs baseline: 3.1322x; 1.2816x over previous
//
#include <hip/hip_runtime.h>
#include <hip/hip_bf16.h>

#define NSEQ 8
#define LSEQ 9216
#define DMODEL 64
#define DIN 128
#define DST 16
#define NCH 144
#define CLEN 64

typedef __attribute__((ext_vector_type(8))) short bf16x8;
typedef __attribute__((ext_vector_type(4))) float f32x4;

__device__ __forceinline__ float bf2fl(unsigned short b) {
  return __uint_as_float(((unsigned)b) << 16);
}
__device__ __forceinline__ unsigned short fl2bf(float f) {
  unsigned u = __float_as_uint(f);
  u += 0x7fffu + ((u >> 16) & 1u);
  return (unsigned short)(u >> 16);
}
__device__ __forceinline__ unsigned pk2(float lo, float hi) {
  return ((unsigned)fl2bf(hi) << 16) | (unsigned)fl2bf(lo);
}
__device__ __forceinline__ void unp8(const uint4 r, float* f) {
  f[0]=__uint_as_float(r.x<<16); f[1]=__uint_as_float(r.x&0xffff0000u);
  f[2]=__uint_as_float(r.y<<16); f[3]=__uint_as_float(r.y&0xffff0000u);
  f[4]=__uint_as_float(r.z<<16); f[5]=__uint_as_float(r.z&0xffff0000u);
  f[6]=__uint_as_float(r.w<<16); f[7]=__uint_as_float(r.w&0xffff0000u);
}
__device__ __forceinline__ float sigm(float x) {
  return __fdividef(1.f, 1.f + __expf(-x));
}

// prep: W2 [160][128] (combined dt/B/C), W1 [256][64] (in_proj), W3 [64][128] (out_proj), all bf16.
__global__ __launch_bounds__(256) void k_prep(
    const float* __restrict__ XW, const float* __restrict__ DW,
    const float* __restrict__ IPW, const float* __restrict__ OPW,
    unsigned short* __restrict__ W2, unsigned short* __restrict__ W1,
    unsigned short* __restrict__ W3)
{
  const int e = blockIdx.x * 256 + threadIdx.x;
  if (e < 160 * 128) {
    const int d = e >> 7, k = e & 127;
    float v;
    if (d < 128) {
      v = 0.f;
#pragma unroll
      for (int r = 0; r < 4; ++r) v = fmaf(DW[d * 4 + r], XW[r * 128 + k], v);
    } else if (d < 144) {
      v = XW[(4 + (d - 128)) * 128 + k];
    } else {
      v = XW[(20 + (d - 144)) * 128 + k];
    }
    W2[e] = fl2bf(v);
  } else if (e < 160 * 128 + 256 * 64) {
    const int e2 = e - 160 * 128;
    W1[e2] = fl2bf(IPW[e2]);
  } else if (e < 160 * 128 + 256 * 64 + 64 * 128) {
    const int e3 = e - 160 * 128 - 256 * 64;
    W3[e3] = fl2bf(OPW[e3]);
  }
}

// K1: LN + in_proj (MFMA, M=80 with 16-token halo) + depthwise conv K=4 + SiLU, fused.
// Outputs: xc (conv'd, silu'd, bf16) and zz (gate, bf16). xs never hits global.
__global__ __launch_bounds__(256, 2) void k_ln_inproj_conv(
    const float* __restrict__ x, const float* __restrict__ nw,
    const float* __restrict__ nb, const uint4* __restrict__ W1,
    const float* __restrict__ cw, const float* __restrict__ cb,
    uint4* __restrict__ xc, unsigned* __restrict__ zz)
{
  __shared__ char ldsA[80 * 128];                 // normalized x, bf16, swizzled
  __shared__ unsigned short xsp[80][132];         // in_proj xs (cols 0..127), rows = halo+64 tokens
  __shared__ unsigned short zzb[64][132];         // z staging (cols 0..127)

  const int tid   = threadIdx.x;
  const int lane  = tid & 63;
  const int w     = tid >> 6;
  const int col16 = lane & 15;
  const int qw    = lane >> 4;
  const int g0    = blockIdx.x * 64;
  const int n     = g0 / LSEQ;
  const int l0    = g0 % LSEQ;

  // phase 1: LN for 80 rows (tokens l0-16 .. l0+63); threads 0..79, 1 row each.
  if (tid < 80) {
    const int l = l0 - 16 + tid;
    const int row = tid;
    if (l < 0) {
      // zero halo rows before sequence start (matches reference zero-padding; in_proj has no bias)
#pragma unroll
      for (int s = 0; s < 8; ++s)
        *(uint4*)(ldsA + row * 128 + ((s ^ (row & 7)) << 4)) = (uint4){0, 0, 0, 0};
    } else {
      const float* xp = x + (size_t)n * DMODEL * LSEQ + l;
      float v[DMODEL];
      float s0 = 0.f;
#pragma unroll
      for (int j = 0; j < DMODEL; ++j) { v[j] = xp[(size_t)j * LSEQ]; s0 += v[j]; }
      const float mu = s0 * (1.f / DMODEL);
      float s1 = 0.f;
#pragma unroll
      for (int j = 0; j < DMODEL; ++j) { float d = v[j] - mu; s1 += d * d; }
      const float rs = rsqrtf(s1 * (1.f / DMODEL) + 1e-6f);
#pragma unroll
      for (int s = 0; s < 8; ++s) {
        float f[8];
#pragma unroll
        for (int e = 0; e < 8; ++e)
          f[e] = (v[s * 8 + e] - mu) * rs * nw[s * 8 + e] + nb[s * 8 + e];
        uint4 pkv;
        pkv.x = pk2(f[0], f[1]); pkv.y = pk2(f[2], f[3]);
        pkv.z = pk2(f[4], f[5]); pkv.w = pk2(f[6], f[7]);
        *(uint4*)(ldsA + row * 128 + ((s ^ (row & 7)) << 4)) = pkv;
      }
    }
  }
  __syncthreads();

  // phase 2: MFMA, 5 M-tiles x 4 N-tiles x 2 K-steps per wave.
  bf16x8 bfr[4][2];
  {
    const uint4* wp = W1 + (size_t)(w * 64 + col16) * 8 + qw;
#pragma unroll
    for (int t = 0; t < 4; ++t)
#pragma unroll
      for (int s = 0; s < 2; ++s) {
        const uint4 u = wp[t * 128 + s * 4];
        bfr[t][s] = *(const bf16x8*)&u;
      }
  }

  f32x4 acc[5][4];
#pragma unroll
  for (int m = 0; m < 5; ++m)
#pragma unroll
    for (int t = 0; t < 4; ++t) acc[m][t] = (f32x4){0.f, 0.f, 0.f, 0.f};

#pragma unroll
  for (int m = 0; m < 5; ++m) {
    const int row = m * 16 + col16;
#pragma unroll
    for (int s = 0; s < 2; ++s) {
      const int slot = qw + s * 4;
      const uint4 u = *(const uint4*)(ldsA + row * 128 + ((slot ^ (row & 7)) << 4));
      const bf16x8 a = *(const bf16x8*)&u;
#pragma unroll
      for (int t = 0; t < 4; ++t)
        acc[m][t] = __builtin_amdgcn_mfma_f32_16x16x32_bf16(a, bfr[t][s], acc[m][t], 0, 0, 0);
    }
  }

  // phase 3: stage outputs. waves 0,1 -> xs (all 80 rows); waves 2,3 -> z (rows 16..79).
  if (w < 2) {
    const int cbase = w * 64;
#pragma unroll
    for (int m = 0; m < 5; ++m)
#pragma unroll
      for (int t = 0; t < 4; ++t) {
        const int c = cbase + t * 16 + col16;
        const int rb = m * 16 + qw * 4;
#pragma unroll
        for (int e = 0; e < 4; ++e)
          xsp[rb + e][c] = fl2bf(acc[m][t][e]);
      }
  } else {
    const int cbase = (w - 2) * 64;
#pragma unroll
    for (int m = 1; m < 5; ++m)
#pragma unroll
      for (int t = 0; t < 4; ++t) {
        const int c = cbase + t * 16 + col16;
        const int rb = (m - 1) * 16 + qw * 4;
#pragma unroll
        for (int e = 0; e < 4; ++e)
          zzb[rb + e][c] = fl2bf(acc[m][t][e]);
      }
  }
  __syncthreads();

  // phase 4: depthwise conv (K=4) + SiLU from LDS xs, write xc.
  {
    const int dg = tid & 15;     // 8-channel group
    const int dl = tid >> 4;     // token sub-index
    const int di0 = dg * 8;
    float wk[4][8], bb[8];
#pragma unroll
    for (int e = 0; e < 8; ++e) {
      bb[e] = cb[di0 + e];
#pragma unroll
      for (int k = 0; k < 4; ++k) wk[k][e] = cw[(di0 + e) * 4 + k];
    }
#pragma unroll
    for (int p = 0; p < 4; ++p) {
      const int u = p * 16 + dl;           // output token 0..63
      const int r = 16 + u;                // LDS row of token u
      float a2[8];
#pragma unroll
      for (int e = 0; e < 8; ++e) a2[e] = bb[e];
#pragma unroll
      for (int k = 0; k < 4; ++k) {
        const uint4 uv = *(const uint4*)&xsp[r - 3 + k][di0];
        float f[8];
        unp8(uv, f);
#pragma unroll
        for (int e = 0; e < 8; ++e) a2[e] = fmaf(f[e], wk[k][e], a2[e]);
      }
      unsigned o[4];
#pragma unroll
      for (int e = 0; e < 8; e += 2) {
        const float y0 = a2[e] * sigm(a2[e]);
        const float y1 = a2[e + 1] * sigm(a2[e + 1]);
        o[e >> 1] = pk2(y0, y1);
      }
      uint4 pkv; pkv.x = o[0]; pkv.y = o[1]; pkv.z = o[2]; pkv.w = o[3];
      xc[(size_t)(g0 + u) * 16 + dg] = pkv;
    }
  }

  // phase 5: coalesced z copy-out.
  unsigned* __restrict__ zg = zz + (size_t)g0 * 64;
  const unsigned* zu = (const unsigned*)&zzb[0][0];
#pragma unroll
  for (int i = 0; i < 16; ++i) {
    const int f = i * 256 + tid;
    zg[f] = zu[(f >> 6) * 66 + (f & 63)];
  }
}

// K3: fused x_proj + dt_proj + softplus as one bf16 MFMA GEMM.
__global__ __launch_bounds__(256, 2) void k_xproj(
    const uint4* __restrict__ xc, const uint4* __restrict__ W2,
    const float* __restrict__ dtb,
    unsigned* __restrict__ dt, float* __restrict__ Bm, float* __restrict__ Cm)
{
  __shared__ char lds[40960];

  const int tid   = threadIdx.x;
  const int lane  = tid & 63;
  const int w     = tid >> 6;
  const int col   = lane & 15;
  const int qw    = lane >> 4;
  const int tok0b = blockIdx.x * 64;
  const int tok0  = tok0b + w * 16;

#pragma unroll
  for (int i = 0; i < 10; ++i) {
    const int gi = i * 256 + tid;
    const int row = gi >> 4, slot = gi & 15;
    const uint4 u = W2[gi];
    *(uint4*)(lds + row * 256 + ((slot ^ (row & 7)) << 4)) = u;
  }
  __syncthreads();

  f32x4 acc[10];
#pragma unroll
  for (int t = 0; t < 10; ++t) acc[t] = (f32x4){0.f, 0.f, 0.f, 0.f};

  {
    const uint4* ap = xc + ((size_t)(tok0 + col)) * 16 + qw;
#pragma unroll
    for (int s = 0; s < 4; ++s) {
      const uint4 ua = ap[s * 4];
      const bf16x8 a = *(const bf16x8*)&ua;
#pragma unroll
      for (int t = 0; t < 10; ++t) {
        const int row = t * 16 + col;
        const int slot = s * 4 + qw;
        const uint4 ub = *(const uint4*)(lds + row * 256 + ((slot ^ (row & 7)) << 4));
        const bf16x8 b = *(const bf16x8*)&ub;
        acc[t] = __builtin_amdgcn_mfma_f32_16x16x32_bf16(a, b, acc[t], 0, 0, 0);
      }
    }
  }
  __syncthreads();

  unsigned short (*dts)[132] = (unsigned short (*)[132])lds;
  float (*bs)[17] = (float (*)[17])(lds + 16896);
  float (*cs)[17] = (float (*)[17])(lds + 16896 + 4352);

  const int tokl = w * 16 + qw * 4;
#pragma unroll
  for (int t = 0; t < 8; ++t) {
    const int d = t * 16 + col;
    const float bias = dtb[d];
#pragma unroll
    for (int e = 0; e < 4; ++e) {
      const float xv = acc[t][e] + bias;
      const float sp = fmaxf(xv, 0.f) + __logf(1.f + __expf(-fabsf(xv)));
      dts[tokl + e][d] = fl2bf(sp);
    }
  }
#pragma unroll
  for (int e = 0; e < 4; ++e) bs[tokl + e][col] = acc[8][e];
#pragma unroll
  for (int e = 0; e < 4; ++e) cs[tokl + e][col] = acc[9][e];
  __syncthreads();

  unsigned* __restrict__ dtg = dt + (size_t)tok0b * 64;
  const unsigned* dfl = (const unsigned*)&dts[0][0];
#pragma unroll
  for (int i = 0; i < 16; ++i) {
    const int f = i * 256 + tid;
    dtg[f] = dfl[(f >> 6) * 66 + (f & 63)];
  }
  float* __restrict__ bg = Bm + (size_t)tok0b * 16;
  float* __restrict__ cg = Cm + (size_t)tok0b * 16;
  const float* bfl = &bs[0][0];
  const float* cfl = &cs[0][0];
#pragma unroll
  for (int i = 0; i < 4; ++i) {
    const int f = i * 256 + tid;
    bg[f] = bfl[f + (f >> 4)];
    cg[f] = cfl[f + (f >> 4)];
  }
}

// K4: scan pass A — per-chunk (prod a, local scan end). thread=(n, chunk, d).
__global__ __launch_bounds__(128) void k_scanA(
    const unsigned short* __restrict__ dtp, const unsigned short* __restrict__ xcp,
    const float* __restrict__ Bm, const float* __restrict__ A_log,
    float* __restrict__ P, float* __restrict__ S)
{
  const int d = threadIdx.x;
  const int c = blockIdx.x;
  const int n = blockIdx.y;

  float Ar[DST];
#pragma unroll
  for (int s = 0; s < DST; ++s) Ar[s] = -__expf(A_log[d * DST + s]);

  float p[DST], h[DST];
#pragma unroll
  for (int s = 0; s < DST; ++s) { p[s] = 1.f; h[s] = 0.f; }

  const size_t tok0 = (size_t)n * LSEQ + (size_t)c * CLEN;
#pragma unroll 2
  for (int i = 0; i < CLEN; ++i) {
    const size_t tok = tok0 + i;
    const float dtv = bf2fl(dtp[tok * DIN + d]);
    const float xcv = bf2fl(xcp[tok * DIN + d]);
    const float bx = dtv * xcv;
    const float4* bmp = reinterpret_cast<const float4*>(Bm + tok * DST);
    const float4 q0 = bmp[0], q1 = bmp[1], q2 = bmp[2], q3 = bmp[3];
    const float bm[DST] = {q0.x,q0.y,q0.z,q0.w, q1.x,q1.y,q1.z,q1.w,
                           q2.x,q2.y,q2.z,q2.w, q3.x,q3.y,q3.z,q3.w};
#pragma unroll
    for (int s = 0; s < DST; ++s) {
      const float a = __expf(dtv * Ar[s]);
      p[s] *= a;
      h[s] = fmaf(a, h[s], bx * bm[s]);
    }
  }
  const size_t ob = (((size_t)n * NCH + c) * DIN + d) * DST;
#pragma unroll
  for (int s = 0; s < DST; ++s) { P[ob + s] = p[s]; S[ob + s] = h[s]; }
}

// K5: sequential carry combine over chunks. thread = (n,d,s) chain.
__global__ __launch_bounds__(256) void k_comb(
    const float* __restrict__ P, const float* __restrict__ S, float* __restrict__ carry)
{
  const int t = blockIdx.x * 256 + threadIdx.x;  // 16384
  const int s = t & 15;
  const int d = (t >> 4) & 127;
  const int n = t >> 11;
  float h = 0.f;
  for (int c = 0; c < NCH; ++c) {
    const size_t idx = (((size_t)n * NCH + c) * DIN + d) * DST + s;
    carry[idx] = h;
    h = fmaf(P[idx], h, S[idx]);
  }
}

// K6: scan pass C — replay with carry-in, fuse y = C·h + D·xc, gate with silu(z). writes yz (bf16).
__global__ __launch_bounds__(128) void k_scanC(
    const unsigned short* __restrict__ dtp, const unsigned short* __restrict__ xcp,
    const unsigned short* __restrict__ zp,
    const float* __restrict__ Bm, const float* __restrict__ Cm,
    const float* __restrict__ A_log, const float* __restrict__ Dp,
    const float* __restrict__ carry, unsigned short* __restrict__ yz)
{
  const int d = threadIdx.x;
  const int c = blockIdx.x;
  const int n = blockIdx.y;

  float Ar[DST];
#pragma unroll
  for (int s = 0; s < DST; ++s) Ar[s] = -__expf(A_log[d * DST + s]);

  float h[DST];
  const size_t cb = (((size_t)n * NCH + c) * DIN + d) * DST;
#pragma unroll
  for (int s = 0; s < DST; ++s) h[s] = carry[cb + s];
  const float Dv = Dp[d];

  const size_t tok0 = (size_t)n * LSEQ + (size_t)c * CLEN;
#pragma unroll 2
  for (int i = 0; i < CLEN; ++i) {
    const size_t tok = tok0 + i;
    const float dtv = bf2fl(dtp[tok * DIN + d]);
    const float xcv = bf2fl(xcp[tok * DIN + d]);
    const float zv  = bf2fl(zp[tok * DIN + d]);
    const float bx = dtv * xcv;
    const float4* bmp = reinterpret_cast<const float4*>(Bm + tok * DST);
    const float4 b0 = bmp[0], b1 = bmp[1], b2 = bmp[2], b3 = bmp[3];
    const float bm[DST] = {b0.x,b0.y,b0.z,b0.w, b1.x,b1.y,b1.z,b1.w,
                           b2.x,b2.y,b2.z,b2.w, b3.x,b3.y,b3.z,b3.w};
    const float4* cmp = reinterpret_cast<const float4*>(Cm + tok * DST);
    const float4 c0 = cmp[0], c1 = cmp[1], c2 = cmp[2], c3 = cmp[3];
    const float cm[DST] = {c0.x,c0.y,c0.z,c0.w, c1.x,c1.y,c1.z,c1.w,
                           c2.x,c2.y,c2.z,c2.w, c3.x,c3.y,c3.z,c3.w};
    float y = Dv * xcv;
#pragma unroll
    for (int s = 0; s < DST; ++s) {
      const float a = __expf(dtv * Ar[s]);
      h[s] = fmaf(a, h[s], bx * bm[s]);
      y = fmaf(h[s], cm[s], y);
    }
    const float o = y * (zv * sigm(zv));
    yz[tok * DIN + d] = fl2bf(o);
  }
}

// K7: out_proj (128->64) + residual as bf16 MFMA GEMM + coalesced epilogue.
__global__ __launch_bounds__(256, 4) void k_outproj(
    const uint4* __restrict__ yz, const uint4* __restrict__ W3,
    const float* __restrict__ xin, float* __restrict__ out)
{
  __shared__ char lds[16896];   // W3 staging (16384 B), then sbuf[64][66] f32 (16896 B)

  const int tid  = threadIdx.x;
  const int lane = tid & 63;
  const int w    = tid >> 6;
  const int col  = lane & 15;
  const int qw   = lane >> 4;
  const int g0   = blockIdx.x * 64;
  const int n    = g0 / LSEQ;
  const int l0   = g0 % LSEQ;

#pragma unroll
  for (int i = 0; i < 4; ++i) {
    const int gi = i * 256 + tid;
    const int row = gi >> 4, slot = gi & 15;
    const uint4 u = W3[gi];
    *(uint4*)(lds + row * 256 + ((slot ^ (row & 7)) << 4)) = u;
  }
  __syncthreads();

  f32x4 acc[4];
#pragma unroll
  for (int t = 0; t < 4; ++t) acc[t] = (f32x4){0.f, 0.f, 0.f, 0.f};

  {
    const uint4* ap = yz + ((size_t)(g0 + w * 16 + col)) * 16 + qw;
#pragma unroll
    for (int s = 0; s < 4; ++s) {
      const uint4 ua = ap[s * 4];
      const bf16x8 a = *(const bf16x8*)&ua;
#pragma unroll
      for (int t = 0; t < 4; ++t) {
        const int row = t * 16 + col;
        const int slot = s * 4 + qw;
        const uint4 ub = *(const uint4*)(lds + row * 256 + ((slot ^ (row & 7)) << 4));
        const bf16x8 b = *(const bf16x8*)&ub;
        acc[t] = __builtin_amdgcn_mfma_f32_16x16x32_bf16(a, b, acc[t], 0, 0, 0);
      }
    }
  }
  __syncthreads();

  float (*sbuf)[66] = (float (*)[66])lds;
  const int tokl = w * 16 + qw * 4;
#pragma unroll
  for (int t = 0; t < 4; ++t) {
    const int c = t * 16 + col;
#pragma unroll
    for (int e = 0; e < 4; ++e) sbuf[tokl + e][c] = acc[t][e];
  }
  __syncthreads();

#pragma unroll
  for (int i = 0; i < 16; ++i) {
    const int f = i * 256 + tid;
    const int ch = f >> 6, tk = f & 63;
    const size_t g = ((size_t)(n * DMODEL + ch)) * LSEQ + l0 + tk;
    out[g] = xin[g] + sbuf[tk][ch];
  }
}

extern "C" void kernel_launch(void* const* d_in, const int* in_sizes, int n_in,
                              void* d_out, int out_size, void* d_ws, size_t ws_size,
                              hipStream_t stream)
{
  const float* x    = (const float*)d_in[0];
  const float* nw   = (const float*)d_in[1];
  const float* nb   = (const float*)d_in[2];
  const float* ipw  = (const float*)d_in[3];
  const float* cw   = (const float*)d_in[4];
  const float* cb   = (const float*)d_in[5];
  const float* xpw  = (const float*)d_in[6];
  const float* dpw  = (const float*)d_in[7];
  const float* dpb  = (const float*)d_in[8];
  const float* alog = (const float*)d_in[9];
  const float* dpar = (const float*)d_in[10];
  const float* opw  = (const float*)d_in[11];
  float* out = (float*)d_out;

  char* w = (char*)d_ws;
  const size_t tokch = (size_t)NSEQ * LSEQ * DIN;        // 9,437,184 elements
  unsigned short* zz = (unsigned short*)w; w += tokch * 2;
  unsigned short* xc = (unsigned short*)w; w += tokch * 2;
  unsigned short* dt = (unsigned short*)w; w += tokch * 2;
  float* Bm = (float*)w;    w += (size_t)NSEQ * LSEQ * DST * 4;
  float* Cm = (float*)w;    w += (size_t)NSEQ * LSEQ * DST * 4;
  float* P  = (float*)w;    w += (size_t)NSEQ * NCH * DIN * DST * 4;
  float* S  = (float*)w;    w += (size_t)NSEQ * NCH * DIN * DST * 4;
  float* carry = (float*)w; w += (size_t)NSEQ * NCH * DIN * DST * 4;
  unsigned short* yz = (unsigned short*)w; w += tokch * 2;
  unsigned short* W2 = (unsigned short*)w; w += (size_t)160 * 128 * 2;
  unsigned short* W1 = (unsigned short*)w; w += (size_t)256 * 64 * 2;
  unsigned short* W3 = (unsigned short*)w; w += (size_t)64 * 128 * 2;

  k_prep<<<dim3(176), 256, 0, stream>>>(xpw, dpw, ipw, opw, W2, W1, W3);
  k_ln_inproj_conv<<<dim3((NSEQ * LSEQ) / 64), 256, 0, stream>>>(
      x, nw, nb, (const uint4*)W1, cw, cb, (uint4*)xc, (unsigned*)zz);
  k_xproj<<<dim3((NSEQ * LSEQ) / 64), 256, 0, stream>>>(
      (const uint4*)xc, (const uint4*)W2, dpb, (unsigned*)dt, Bm, Cm);
  k_scanA<<<dim3(NCH, NSEQ), 128, 0, stream>>>(dt, xc, Bm, alog, P, S);
  k_comb<<<dim3((NSEQ * DIN * DST) / 256), 256, 0, stream>>>(P, S, carry);
  k_scanC<<<dim3(NCH, NSEQ), 128, 0, stream>>>(dt, xc, zz, Bm, Cm, alog, dpar, carry, yz);
  k_outproj<<<dim3((NSEQ * LSEQ) / 64), 256, 0, stream>>>(
      (const uint4*)yz, (const uint4*)W3, x, out);
}

// Round 8
// 187.708 us; speedup vs baseline: 3.1491x; 1.0054x over previous
//
#include <hip/hip_runtime.h>
#include <hip/hip_bf16.h>

#define NSEQ 8
#define LSEQ 9216
#define DMODEL 64
#define DIN 128
#define DST 16
#define NCH 288
#define CLEN 32

typedef __attribute__((ext_vector_type(8))) short bf16x8;
typedef __attribute__((ext_vector_type(4))) float f32x4;

__device__ __forceinline__ float bf2fl(unsigned short b) {
  return __uint_as_float(((unsigned)b) << 16);
}
__device__ __forceinline__ unsigned short fl2bf(float f) {
  unsigned u = __float_as_uint(f);
  u += 0x7fffu + ((u >> 16) & 1u);
  return (unsigned short)(u >> 16);
}
__device__ __forceinline__ unsigned pk2(float lo, float hi) {
  return ((unsigned)fl2bf(hi) << 16) | (unsigned)fl2bf(lo);
}
__device__ __forceinline__ void unp8(const uint4 r, float* f) {
  f[0]=__uint_as_float(r.x<<16); f[1]=__uint_as_float(r.x&0xffff0000u);
  f[2]=__uint_as_float(r.y<<16); f[3]=__uint_as_float(r.y&0xffff0000u);
  f[4]=__uint_as_float(r.z<<16); f[5]=__uint_as_float(r.z&0xffff0000u);
  f[6]=__uint_as_float(r.w<<16); f[7]=__uint_as_float(r.w&0xffff0000u);
}
__device__ __forceinline__ float sigm(float x) {
  return __fdividef(1.f, 1.f + __expf(-x));
}

// prep: W2 [160][128] (combined dt/B/C), W1 [256][64] (in_proj), W3 [64][128] (out_proj), all bf16.
__global__ __launch_bounds__(256) void k_prep(
    const float* __restrict__ XW, const float* __restrict__ DW,
    const float* __restrict__ IPW, const float* __restrict__ OPW,
    unsigned short* __restrict__ W2, unsigned short* __restrict__ W1,
    unsigned short* __restrict__ W3)
{
  const int e = blockIdx.x * 256 + threadIdx.x;
  if (e < 160 * 128) {
    const int d = e >> 7, k = e & 127;
    float v;
    if (d < 128) {
      v = 0.f;
#pragma unroll
      for (int r = 0; r < 4; ++r) v = fmaf(DW[d * 4 + r], XW[r * 128 + k], v);
    } else if (d < 144) {
      v = XW[(4 + (d - 128)) * 128 + k];
    } else {
      v = XW[(20 + (d - 144)) * 128 + k];
    }
    W2[e] = fl2bf(v);
  } else if (e < 160 * 128 + 256 * 64) {
    const int e2 = e - 160 * 128;
    W1[e2] = fl2bf(IPW[e2]);
  } else if (e < 160 * 128 + 256 * 64 + 64 * 128) {
    const int e3 = e - 160 * 128 - 256 * 64;
    W3[e3] = fl2bf(OPW[e3]);
  }
}

// K1: LN + in_proj (MFMA, M=80 with 16-token halo) + depthwise conv K=4 + SiLU, fused.
// LDS: region0 (16896 B) = LN A-tile (phases 1-2) then z staging (phases 3-5);
//      xsp [80][136] (21760 B) for conv input. Total 38656 B -> 4 blocks/CU.
__global__ __launch_bounds__(256, 4) void k_ln_inproj_conv(
    const float* __restrict__ x, const float* __restrict__ nw,
    const float* __restrict__ nb, const uint4* __restrict__ W1,
    const float* __restrict__ cw, const float* __restrict__ cb,
    uint4* __restrict__ xc, unsigned* __restrict__ zz)
{
  __shared__ char ldsR0[16896];            // ldsA (80*128=10240) then zzb[64][132]
  __shared__ unsigned short xsp[80][136];  // in_proj xs rows = halo+64 tokens

  const int tid   = threadIdx.x;
  const int lane  = tid & 63;
  const int w     = tid >> 6;
  const int col16 = lane & 15;
  const int qw    = lane >> 4;
  const int g0    = blockIdx.x * 64;
  const int n     = g0 / LSEQ;
  const int l0    = g0 % LSEQ;

  // phase 1: LN for 80 rows; 160 threads, 2 per row (32 channels each + shfl combine).
  if (tid < 160) {
    const int row  = tid >> 1;
    const int half = tid & 1;
    const int l = l0 - 16 + row;
    if (l >= 0) {
      const float* xp = x + (size_t)n * DMODEL * LSEQ + l;
      float f[32];
      float s0 = 0.f;
#pragma unroll
      for (int j = 0; j < 32; ++j) { f[j] = xp[(size_t)(half * 32 + j) * LSEQ]; s0 += f[j]; }
      s0 += __shfl_xor(s0, 1);
      const float mu = s0 * (1.f / DMODEL);
      float s1 = 0.f;
#pragma unroll
      for (int j = 0; j < 32; ++j) { float d = f[j] - mu; s1 += d * d; }
      s1 += __shfl_xor(s1, 1);
      const float rs = rsqrtf(s1 * (1.f / DMODEL) + 1e-6f);
#pragma unroll
      for (int s = 0; s < 4; ++s) {
        float g[8];
#pragma unroll
        for (int e = 0; e < 8; ++e) {
          const int j = half * 32 + s * 8 + e;
          g[e] = (f[s * 8 + e] - mu) * rs * nw[j] + nb[j];
        }
        uint4 pkv;
        pkv.x = pk2(g[0], g[1]); pkv.y = pk2(g[2], g[3]);
        pkv.z = pk2(g[4], g[5]); pkv.w = pk2(g[6], g[7]);
        const int slot = half * 4 + s;
        *(uint4*)(ldsR0 + row * 128 + ((slot ^ (row & 7)) << 4)) = pkv;
      }
    } else {
#pragma unroll
      for (int s = 0; s < 4; ++s) {
        const int slot = half * 4 + s;
        *(uint4*)(ldsR0 + row * 128 + ((slot ^ (row & 7)) << 4)) = (uint4){0, 0, 0, 0};
      }
    }
  }
  __syncthreads();

  // phase 2: MFMA, 5 M-tiles x 4 N-tiles x 2 K-steps per wave.
  bf16x8 bfr[4][2];
  {
    const uint4* wp = W1 + (size_t)(w * 64 + col16) * 8 + qw;
#pragma unroll
    for (int t = 0; t < 4; ++t)
#pragma unroll
      for (int s = 0; s < 2; ++s) {
        const uint4 u = wp[t * 128 + s * 4];
        bfr[t][s] = *(const bf16x8*)&u;
      }
  }

  f32x4 acc[5][4];
#pragma unroll
  for (int m = 0; m < 5; ++m)
#pragma unroll
    for (int t = 0; t < 4; ++t) acc[m][t] = (f32x4){0.f, 0.f, 0.f, 0.f};

#pragma unroll
  for (int m = 0; m < 5; ++m) {
    const int row = m * 16 + col16;
#pragma unroll
    for (int s = 0; s < 2; ++s) {
      const int slot = qw + s * 4;
      const uint4 u = *(const uint4*)(ldsR0 + row * 128 + ((slot ^ (row & 7)) << 4));
      const bf16x8 a = *(const bf16x8*)&u;
#pragma unroll
      for (int t = 0; t < 4; ++t)
        acc[m][t] = __builtin_amdgcn_mfma_f32_16x16x32_bf16(a, bfr[t][s], acc[m][t], 0, 0, 0);
    }
  }
  __syncthreads();   // ldsA dead; zzb may now overwrite region0

  // phase 3: stage outputs. waves 0,1 -> xsp (80 rows); waves 2,3 -> zzb (rows 16..79).
  unsigned short (*zzb)[132] = (unsigned short (*)[132])ldsR0;
  if (w < 2) {
    const int cbase = w * 64;
#pragma unroll
    for (int m = 0; m < 5; ++m)
#pragma unroll
      for (int t = 0; t < 4; ++t) {
        const int c = cbase + t * 16 + col16;
        const int rb = m * 16 + qw * 4;
#pragma unroll
        for (int e = 0; e < 4; ++e)
          xsp[rb + e][c] = fl2bf(acc[m][t][e]);
      }
  } else {
    const int cbase = (w - 2) * 64;
#pragma unroll
    for (int m = 1; m < 5; ++m)
#pragma unroll
      for (int t = 0; t < 4; ++t) {
        const int c = cbase + t * 16 + col16;
        const int rb = (m - 1) * 16 + qw * 4;
#pragma unroll
        for (int e = 0; e < 4; ++e)
          zzb[rb + e][c] = fl2bf(acc[m][t][e]);
      }
  }
  __syncthreads();

  // phase 4: depthwise conv (K=4) + SiLU from LDS xs, write xc.
  {
    const int dg = tid & 15;     // 8-channel group
    const int dl = tid >> 4;     // token sub-index (0..15)
    const int di0 = dg * 8;
    float wk[4][8], bb[8];
#pragma unroll
    for (int e = 0; e < 8; ++e) {
      bb[e] = cb[di0 + e];
#pragma unroll
      for (int k = 0; k < 4; ++k) wk[k][e] = cw[(di0 + e) * 4 + k];
    }
#pragma unroll
    for (int p = 0; p < 4; ++p) {
      const int u = p * 16 + dl;           // output token 0..63
      const int r = 16 + u;                // LDS row of token u
      float a2[8];
#pragma unroll
      for (int e = 0; e < 8; ++e) a2[e] = bb[e];
#pragma unroll
      for (int k = 0; k < 4; ++k) {
        const uint4 uv = *(const uint4*)&xsp[r - 3 + k][di0];
        float f[8];
        unp8(uv, f);
#pragma unroll
        for (int e = 0; e < 8; ++e) a2[e] = fmaf(f[e], wk[k][e], a2[e]);
      }
      unsigned o[4];
#pragma unroll
      for (int e = 0; e < 8; e += 2) {
        const float y0 = a2[e] * sigm(a2[e]);
        const float y1 = a2[e + 1] * sigm(a2[e + 1]);
        o[e >> 1] = pk2(y0, y1);
      }
      uint4 pkv; pkv.x = o[0]; pkv.y = o[1]; pkv.z = o[2]; pkv.w = o[3];
      xc[(size_t)(g0 + u) * 16 + dg] = pkv;
    }
  }

  // phase 5: coalesced z copy-out.
  unsigned* __restrict__ zg = zz + (size_t)g0 * 64;
  const unsigned* zu = (const unsigned*)ldsR0;
#pragma unroll
  for (int i = 0; i < 16; ++i) {
    const int f = i * 256 + tid;
    zg[f] = zu[(f >> 6) * 66 + (f & 63)];
  }
}

// K3: fused x_proj + dt_proj + softplus as one bf16 MFMA GEMM.
__global__ __launch_bounds__(256, 2) void k_xproj(
    const uint4* __restrict__ xc, const uint4* __restrict__ W2,
    const float* __restrict__ dtb,
    unsigned* __restrict__ dt, float* __restrict__ Bm, float* __restrict__ Cm)
{
  __shared__ char lds[40960];

  const int tid   = threadIdx.x;
  const int lane  = tid & 63;
  const int w     = tid >> 6;
  const int col   = lane & 15;
  const int qw    = lane >> 4;
  const int tok0b = blockIdx.x * 64;
  const int tok0  = tok0b + w * 16;

#pragma unroll
  for (int i = 0; i < 10; ++i) {
    const int gi = i * 256 + tid;
    const int row = gi >> 4, slot = gi & 15;
    const uint4 u = W2[gi];
    *(uint4*)(lds + row * 256 + ((slot ^ (row & 7)) << 4)) = u;
  }
  __syncthreads();

  f32x4 acc[10];
#pragma unroll
  for (int t = 0; t < 10; ++t) acc[t] = (f32x4){0.f, 0.f, 0.f, 0.f};

  {
    const uint4* ap = xc + ((size_t)(tok0 + col)) * 16 + qw;
#pragma unroll
    for (int s = 0; s < 4; ++s) {
      const uint4 ua = ap[s * 4];
      const bf16x8 a = *(const bf16x8*)&ua;
#pragma unroll
      for (int t = 0; t < 10; ++t) {
        const int row = t * 16 + col;
        const int slot = s * 4 + qw;
        const uint4 ub = *(const uint4*)(lds + row * 256 + ((slot ^ (row & 7)) << 4));
        const bf16x8 b = *(const bf16x8*)&ub;
        acc[t] = __builtin_amdgcn_mfma_f32_16x16x32_bf16(a, b, acc[t], 0, 0, 0);
      }
    }
  }
  __syncthreads();

  unsigned short (*dts)[132] = (unsigned short (*)[132])lds;
  float (*bs)[17] = (float (*)[17])(lds + 16896);
  float (*cs)[17] = (float (*)[17])(lds + 16896 + 4352);

  const int tokl = w * 16 + qw * 4;
#pragma unroll
  for (int t = 0; t < 8; ++t) {
    const int d = t * 16 + col;
    const float bias = dtb[d];
#pragma unroll
    for (int e = 0; e < 4; ++e) {
      const float xv = acc[t][e] + bias;
      const float sp = fmaxf(xv, 0.f) + __logf(1.f + __expf(-fabsf(xv)));
      dts[tokl + e][d] = fl2bf(sp);
    }
  }
#pragma unroll
  for (int e = 0; e < 4; ++e) bs[tokl + e][col] = acc[8][e];
#pragma unroll
  for (int e = 0; e < 4; ++e) cs[tokl + e][col] = acc[9][e];
  __syncthreads();

  unsigned* __restrict__ dtg = dt + (size_t)tok0b * 64;
  const unsigned* dfl = (const unsigned*)&dts[0][0];
#pragma unroll
  for (int i = 0; i < 16; ++i) {
    const int f = i * 256 + tid;
    dtg[f] = dfl[(f >> 6) * 66 + (f & 63)];
  }
  float* __restrict__ bg = Bm + (size_t)tok0b * 16;
  float* __restrict__ cg = Cm + (size_t)tok0b * 16;
  const float* bfl = &bs[0][0];
  const float* cfl = &cs[0][0];
#pragma unroll
  for (int i = 0; i < 4; ++i) {
    const int f = i * 256 + tid;
    bg[f] = bfl[f + (f >> 4)];
    cg[f] = cfl[f + (f >> 4)];
  }
}

// K4: scan pass A — per-chunk (prod a, local scan end). thread=(n, chunk, d).
__global__ __launch_bounds__(128) void k_scanA(
    const unsigned short* __restrict__ dtp, const unsigned short* __restrict__ xcp,
    const float* __restrict__ Bm, const float* __restrict__ A_log,
    float* __restrict__ P, float* __restrict__ S)
{
  const int d = threadIdx.x;
  const int c = blockIdx.x;
  const int n = blockIdx.y;

  float Ar[DST];
#pragma unroll
  for (int s = 0; s < DST; ++s) Ar[s] = -__expf(A_log[d * DST + s]);

  float p[DST], h[DST];
#pragma unroll
  for (int s = 0; s < DST; ++s) { p[s] = 1.f; h[s] = 0.f; }

  const size_t tok0 = (size_t)n * LSEQ + (size_t)c * CLEN;
#pragma unroll 2
  for (int i = 0; i < CLEN; ++i) {
    const size_t tok = tok0 + i;
    const float dtv = bf2fl(dtp[tok * DIN + d]);
    const float xcv = bf2fl(xcp[tok * DIN + d]);
    const float bx = dtv * xcv;
    const float4* bmp = reinterpret_cast<const float4*>(Bm + tok * DST);
    const float4 q0 = bmp[0], q1 = bmp[1], q2 = bmp[2], q3 = bmp[3];
    const float bm[DST] = {q0.x,q0.y,q0.z,q0.w, q1.x,q1.y,q1.z,q1.w,
                           q2.x,q2.y,q2.z,q2.w, q3.x,q3.y,q3.z,q3.w};
#pragma unroll
    for (int s = 0; s < DST; ++s) {
      const float a = __expf(dtv * Ar[s]);
      p[s] *= a;
      h[s] = fmaf(a, h[s], bx * bm[s]);
    }
  }
  const size_t ob = (((size_t)n * NCH + c) * DIN + d) * DST;
#pragma unroll
  for (int s = 0; s < DST; ++s) { P[ob + s] = p[s]; S[ob + s] = h[s]; }
}

// K5: sequential carry combine over chunks. thread = (n,d,s) chain.
__global__ __launch_bounds__(256) void k_comb(
    const float* __restrict__ P, const float* __restrict__ S, float* __restrict__ carry)
{
  const int t = blockIdx.x * 256 + threadIdx.x;  // 16384
  const int s = t & 15;
  const int d = (t >> 4) & 127;
  const int n = t >> 11;
  float h = 0.f;
  for (int c = 0; c < NCH; ++c) {
    const size_t idx = (((size_t)n * NCH + c) * DIN + d) * DST + s;
    carry[idx] = h;
    h = fmaf(P[idx], h, S[idx]);
  }
}

// K6: scan pass C — replay with carry-in, fuse y = C·h + D·xc, gate with silu(z). writes yz (bf16).
__global__ __launch_bounds__(128) void k_scanC(
    const unsigned short* __restrict__ dtp, const unsigned short* __restrict__ xcp,
    const unsigned short* __restrict__ zp,
    const float* __restrict__ Bm, const float* __restrict__ Cm,
    const float* __restrict__ A_log, const float* __restrict__ Dp,
    const float* __restrict__ carry, unsigned short* __restrict__ yz)
{
  const int d = threadIdx.x;
  const int c = blockIdx.x;
  const int n = blockIdx.y;

  float Ar[DST];
#pragma unroll
  for (int s = 0; s < DST; ++s) Ar[s] = -__expf(A_log[d * DST + s]);

  float h[DST];
  const size_t cb = (((size_t)n * NCH + c) * DIN + d) * DST;
#pragma unroll
  for (int s = 0; s < DST; ++s) h[s] = carry[cb + s];
  const float Dv = Dp[d];

  const size_t tok0 = (size_t)n * LSEQ + (size_t)c * CLEN;
#pragma unroll 2
  for (int i = 0; i < CLEN; ++i) {
    const size_t tok = tok0 + i;
    const float dtv = bf2fl(dtp[tok * DIN + d]);
    const float xcv = bf2fl(xcp[tok * DIN + d]);
    const float zv  = bf2fl(zp[tok * DIN + d]);
    const float bx = dtv * xcv;
    const float4* bmp = reinterpret_cast<const float4*>(Bm + tok * DST);
    const float4 b0 = bmp[0], b1 = bmp[1], b2 = bmp[2], b3 = bmp[3];
    const float bm[DST] = {b0.x,b0.y,b0.z,b0.w, b1.x,b1.y,b1.z,b1.w,
                           b2.x,b2.y,b2.z,b2.w, b3.x,b3.y,b3.z,b3.w};
    const float4* cmp = reinterpret_cast<const float4*>(Cm + tok * DST);
    const float4 c0 = cmp[0], c1 = cmp[1], c2 = cmp[2], c3 = cmp[3];
    const float cm[DST] = {c0.x,c0.y,c0.z,c0.w, c1.x,c1.y,c1.z,c1.w,
                           c2.x,c2.y,c2.z,c2.w, c3.x,c3.y,c3.z,c3.w};
    float y = Dv * xcv;
#pragma unroll
    for (int s = 0; s < DST; ++s) {
      const float a = __expf(dtv * Ar[s]);
      h[s] = fmaf(a, h[s], bx * bm[s]);
      y = fmaf(h[s], cm[s], y);
    }
    const float o = y * (zv * sigm(zv));
    yz[tok * DIN + d] = fl2bf(o);
  }
}

// K7: out_proj (128->64) + residual as bf16 MFMA GEMM + coalesced epilogue.
__global__ __launch_bounds__(256, 4) void k_outproj(
    const uint4* __restrict__ yz, const uint4* __restrict__ W3,
    const float* __restrict__ xin, float* __restrict__ out)
{
  __shared__ char lds[16896];   // W3 staging (16384 B), then sbuf[64][66] f32 (16896 B)

  const int tid  = threadIdx.x;
  const int lane = tid & 63;
  const int w    = tid >> 6;
  const int col  = lane & 15;
  const int qw   = lane >> 4;
  const int g0   = blockIdx.x * 64;
  const int n    = g0 / LSEQ;
  const int l0   = g0 % LSEQ;

#pragma unroll
  for (int i = 0; i < 4; ++i) {
    const int gi = i * 256 + tid;
    const int row = gi >> 4, slot = gi & 15;
    const uint4 u = W3[gi];
    *(uint4*)(lds + row * 256 + ((slot ^ (row & 7)) << 4)) = u;
  }
  __syncthreads();

  f32x4 acc[4];
#pragma unroll
  for (int t = 0; t < 4; ++t) acc[t] = (f32x4){0.f, 0.f, 0.f, 0.f};

  {
    const uint4* ap = yz + ((size_t)(g0 + w * 16 + col)) * 16 + qw;
#pragma unroll
    for (int s = 0; s < 4; ++s) {
      const uint4 ua = ap[s * 4];
      const bf16x8 a = *(const bf16x8*)&ua;
#pragma unroll
      for (int t = 0; t < 4; ++t) {
        const int row = t * 16 + col;
        const int slot = s * 4 + qw;
        const uint4 ub = *(const uint4*)(lds + row * 256 + ((slot ^ (row & 7)) << 4));
        const bf16x8 b = *(const bf16x8*)&ub;
        acc[t] = __builtin_amdgcn_mfma_f32_16x16x32_bf16(a, b, acc[t], 0, 0, 0);
      }
    }
  }
  __syncthreads();

  float (*sbuf)[66] = (float (*)[66])lds;
  const int tokl = w * 16 + qw * 4;
#pragma unroll
  for (int t = 0; t < 4; ++t) {
    const int c = t * 16 + col;
#pragma unroll
    for (int e = 0; e < 4; ++e) sbuf[tokl + e][c] = acc[t][e];
  }
  __syncthreads();

#pragma unroll
  for (int i = 0; i < 16; ++i) {
    const int f = i * 256 + tid;
    const int ch = f >> 6, tk = f & 63;
    const size_t g = ((size_t)(n * DMODEL + ch)) * LSEQ + l0 + tk;
    out[g] = xin[g] + sbuf[tk][ch];
  }
}

extern "C" void kernel_launch(void* const* d_in, const int* in_sizes, int n_in,
                              void* d_out, int out_size, void* d_ws, size_t ws_size,
                              hipStream_t stream)
{
  const float* x    = (const float*)d_in[0];
  const float* nw   = (const float*)d_in[1];
  const float* nb   = (const float*)d_in[2];
  const float* ipw  = (const float*)d_in[3];
  const float* cw   = (const float*)d_in[4];
  const float* cb   = (const float*)d_in[5];
  const float* xpw  = (const float*)d_in[6];
  const float* dpw  = (const float*)d_in[7];
  const float* dpb  = (const float*)d_in[8];
  const float* alog = (const float*)d_in[9];
  const float* dpar = (const float*)d_in[10];
  const float* opw  = (const float*)d_in[11];
  float* out = (float*)d_out;

  char* w = (char*)d_ws;
  const size_t tokch   = (size_t)NSEQ * LSEQ * DIN;          // 9,437,184
  const size_t chunkst = (size_t)NSEQ * NCH * DIN * DST;     // 4,718,592
  unsigned short* zz = (unsigned short*)w; w += tokch * 2;
  unsigned short* xc = (unsigned short*)w; w += tokch * 2;
  unsigned short* dt = (unsigned short*)w; w += tokch * 2;
  float* Bm = (float*)w;    w += (size_t)NSEQ * LSEQ * DST * 4;
  float* Cm = (float*)w;    w += (size_t)NSEQ * LSEQ * DST * 4;
  float* P  = (float*)w;    w += chunkst * 4;
  float* S  = (float*)w;    w += chunkst * 4;
  float* carry = (float*)w; w += chunkst * 4;
  unsigned short* W2 = (unsigned short*)w; w += (size_t)160 * 128 * 2;
  unsigned short* W1 = (unsigned short*)w; w += (size_t)256 * 64 * 2;
  unsigned short* W3 = (unsigned short*)w; w += (size_t)64 * 128 * 2;
  // yz aliases P: P is dead after k_comb, yz written by k_scanC afterwards.
  unsigned short* yz = (unsigned short*)P;

  k_prep<<<dim3(176), 256, 0, stream>>>(xpw, dpw, ipw, opw, W2, W1, W3);
  k_ln_inproj_conv<<<dim3((NSEQ * LSEQ) / 64), 256, 0, stream>>>(
      x, nw, nb, (const uint4*)W1, cw, cb, (uint4*)xc, (unsigned*)zz);
  k_xproj<<<dim3((NSEQ * LSEQ) / 64), 256, 0, stream>>>(
      (const uint4*)xc, (const uint4*)W2, dpb, (unsigned*)dt, Bm, Cm);
  k_scanA<<<dim3(NCH, NSEQ), 128, 0, stream>>>(dt, xc, Bm, alog, P, S);
  k_comb<<<dim3((NSEQ * DIN * DST) / 256), 256, 0, stream>>>(P, S, carry);
  k_scanC<<<dim3(NCH, NSEQ), 128, 0, stream>>>(dt, xc, zz, Bm, Cm, alog, dpar, carry, yz);
  k_outproj<<<dim3((NSEQ * LSEQ) / 64), 256, 0, stream>>>(
      (const uint4*)yz, (const uint4*)W3, x, out);
}